// Round 1
// baseline (1168.580 us; speedup 1.0000x reference)
//
#include <hip/hip_runtime.h>
#include <hip/hip_bf16.h>
#include <math.h>

// Dims
#define N_TOK 2048
#define DIMX  1024
#define NH    8
#define DHD   128
#define HIDN  512
#define CHK   64
#define NCH   32

typedef unsigned short u16;
typedef unsigned int   u32;

__device__ __forceinline__ float bflo(u32 u){ return __uint_as_float(u << 16); }
__device__ __forceinline__ float bfhi(u32 u){ return __uint_as_float(u & 0xffff0000u); }
__device__ __forceinline__ float bf2f(u16 v){ return __uint_as_float(((u32)v) << 16); }
__device__ __forceinline__ u16 f2bf(float f){
  u32 u = __float_as_uint(f);
  u += 0x7fffu + ((u >> 16) & 1u);
  return (u16)(u >> 16);
}
__device__ __forceinline__ u32 pack2(float a, float b){
  return (u32)f2bf(a) | ((u32)f2bf(b) << 16);
}
__device__ __forceinline__ float waveRedSum(float v){
  #pragma unroll
  for (int off = 32; off; off >>= 1) v += __shfl_xor(v, off);
  return v;
}

// ---------------- prep kernels ----------------

__global__ __launch_bounds__(256) void k_rmsnorm(const float* __restrict__ x,
    const float* __restrict__ wst, const float* __restrict__ wrt,
    float* __restrict__ s_, float* __restrict__ r_){
  int row = blockIdx.x, t = threadIdx.x;
  const float4* xr = (const float4*)(x + (size_t)row*DIMX);
  float4 v = xr[t];
  float ss = v.x*v.x + v.y*v.y + v.z*v.z + v.w*v.w;
  ss = waveRedSum(ss);
  __shared__ float red[4];
  int wv = t >> 6, ln = t & 63;
  if (ln == 0) red[wv] = ss;
  __syncthreads();
  float tot = red[0]+red[1]+red[2]+red[3];
  float rr = rsqrtf(tot*(1.f/DIMX) + 1e-6f);
  float4 a = ((const float4*)wst)[t];
  float4 b = ((const float4*)wrt)[t];
  float4 o1 = make_float4(v.x*rr*a.x, v.y*rr*a.y, v.z*rr*a.z, v.w*rr*a.w);
  float4 o2 = make_float4(v.x*rr*b.x, v.y*rr*b.y, v.z*rr*b.z, v.w*rr*b.w);
  ((float4*)(s_ + (size_t)row*DIMX))[t] = o1;
  ((float4*)(r_ + (size_t)row*DIMX))[t] = o2;
}

__global__ __launch_bounds__(256) void k_pool(const float* __restrict__ s_, float* __restrict__ pooled){
  int c = blockIdx.x; int d = blockIdx.y*256 + threadIdx.x;
  float acc = 0.f;
  for (int tt = 0; tt < CHK; ++tt) acc += s_[((size_t)c*CHK+tt)*DIMX + d];
  pooled[(size_t)c*DIMX + d] = acc * (1.f/CHK);
}

__global__ __launch_bounds__(256) void k_lrgate(const float* __restrict__ s_, const float* __restrict__ r_,
    const float* __restrict__ Wstep, const float* __restrict__ bstep,
    const float* __restrict__ gateW,
    float* __restrict__ lrc, float* __restrict__ gate){
  int wv = threadIdx.x >> 6, ln = threadIdx.x & 63;
  int tok = blockIdx.x*4 + wv;
  const float* srow = s_ + (size_t)tok*DIMX;
  const float* rrow = r_ + (size_t)tok*DIMX;
  for (int o = 0; o < 16; ++o){
    int h = o & 7;
    const float* src = (o < 8) ? srow : rrow;
    const float* W = (o < 8) ? Wstep : gateW;
    float acc = 0.f;
    for (int k = ln; k < DIMX; k += 64) acc += src[k]*W[(size_t)k*8+h];
    acc = waveRedSum(acc);
    if (ln == 0){
      if (o < 8){
        float v = 1.f/(1.f+expf(-(acc + bstep[h])));
        lrc[((size_t)h*NCH + (tok>>6))*CHK + (tok&63)] = v;
      } else {
        gate[(size_t)tok*8 + h] = 1.f/(1.f+expf(-acc));
      }
    }
  }
}

__global__ __launch_bounds__(64) void k_momdec(const float* __restrict__ pooled,
    const float* __restrict__ Wmom, const float* __restrict__ bmom,
    const float* __restrict__ Wdec, const float* __restrict__ bdec,
    float* __restrict__ momb, float* __restrict__ decb){
  int c = blockIdx.x, ln = threadIdx.x;
  const float* prow = pooled + (size_t)c*DIMX;
  for (int o = 0; o < 16; ++o){
    int h = o & 7;
    const float* W = (o < 8) ? Wmom : Wdec;
    float acc = 0.f;
    for (int k = ln; k < DIMX; k += 64) acc += prow[k]*W[(size_t)k*8+h];
    acc = waveRedSum(acc);
    if (ln == 0){
      float bb = (o < 8) ? bmom[h] : bdec[h];
      float v = 1.f/(1.f+expf(-(acc+bb)));
      if (o < 8) momb[h*NCH + c] = v; else decb[h*NCH + c] = v;
    }
  }
}

__global__ __launch_bounds__(256) void k_w1t(const float* __restrict__ w1, float* __restrict__ w1t){
  int e = blockIdx.x*256 + threadIdx.x;   // 8*65536
  int h = e >> 16, rem = e & 65535;
  int cc = rem >> 9, k = rem & 511;
  w1t[e] = w1[(size_t)h*65536 + (size_t)k*128 + cc];
}

// ---------------- tiled f32 GEMM: M=2048,N=1024,K=1024 ----------------
// mode 0: plain row-major C. mode 1: chunked QKV layout [h][c][tok][d].
__global__ __launch_bounds__(256) void k_gemm(const float* __restrict__ A, const float* __restrict__ B,
    float* __restrict__ C, int mode){
  __shared__ float As[16][68];
  __shared__ float Bs[16][132];
  int t = threadIdx.x;
  int bm = blockIdx.x * 64, bn = blockIdx.y * 128;
  int tm = (t >> 4) * 4, tn = (t & 15) * 8;
  float acc[4][8] = {};
  for (int k0 = 0; k0 < 1024; k0 += 16){
    { int row = t >> 2, c4 = (t & 3) * 4;
      float4 v = *(const float4*)(A + (size_t)(bm+row)*1024 + k0 + c4);
      As[c4+0][row]=v.x; As[c4+1][row]=v.y; As[c4+2][row]=v.z; As[c4+3][row]=v.w; }
    #pragma unroll
    for (int i = 0; i < 2; ++i){ int f = t + 256*i; int row = f >> 5, c4 = (f & 31)*4;
      *(float4*)&Bs[row][c4] = *(const float4*)(B + (size_t)(k0+row)*1024 + bn + c4); }
    __syncthreads();
    #pragma unroll
    for (int kk = 0; kk < 16; ++kk){
      float a0[4], b0[8];
      *(float4*)a0 = *(const float4*)&As[kk][tm];
      *(float4*)b0 = *(const float4*)&Bs[kk][tn];
      *(float4*)(b0+4) = *(const float4*)&Bs[kk][tn+4];
      #pragma unroll
      for (int i = 0; i < 4; ++i)
        #pragma unroll
        for (int j = 0; j < 8; ++j) acc[i][j] += a0[i]*b0[j];
    }
    __syncthreads();
  }
  for (int i = 0; i < 4; ++i){
    int m = bm + tm + i;
    for (int j = 0; j < 8; ++j){
      int n = bn + tn + j;
      if (mode == 0) C[(size_t)m*1024 + n] = acc[i][j];
      else { int cI = m>>6, tok = m&63, h = n>>7, d = n&127;
        C[(((size_t)(h*NCH+cI))*CHK + tok)*DHD + d] = acc[i][j]; }
    }
  }
}

// ---------------- per-(head,chunk) gradient ----------------
// surprise = -grad of chunk loss wrt (w0,w1,g), evaluated at initial weights.
__global__ __launch_bounds__(256) void k_grad(
    const float* __restrict__ Kc, const float* __restrict__ Vc, const float* __restrict__ lrc,
    const float* __restrict__ mw0, const float* __restrict__ mw1, const float* __restrict__ w1T,
    const float* __restrict__ mg,
    u16* __restrict__ SW0, u16* __restrict__ SW1, float* __restrict__ SG){
  extern __shared__ char smem[];
  u16* a_s  = (u16*)smem;           // [64][512] gelu(u); later du
  u16* up_s = a_s + 64*512;         // [64][512] gelu'(u)
  u16* kc_s = up_s + 64*512;        // [64][128]
  u16* dh_s = kc_s + 64*128;        // [64][128]

  int c = blockIdx.x, bh = blockIdx.y, t = threadIdx.x;
  size_t bc = (size_t)bh*NCH + c;
  const float* kc_g = Kc + bc*(CHK*DHD);
  const float* vc_g = Vc + bc*(CHK*DHD);
  const float* lr_g = lrc + bc*CHK;
  const float* w0 = mw0 + (size_t)bh*(DHD*HIDN);
  const float* w1 = mw1 + (size_t)bh*(HIDN*DHD);
  const float* w1t = w1T + (size_t)bh*(DHD*HIDN);
  const float* g = mg + (size_t)bh*DHD;
  u16* sw0 = SW0 + bc*(DHD*HIDN);
  u16* sw1 = SW1 + bc*(HIDN*DHD);
  float* sg = SG + bc*DHD;

  // P1: kc -> LDS
  #pragma unroll
  for (int i = 0; i < 32; ++i){ int idx = t + 256*i; kc_s[idx] = f2bf(kc_g[idx]); }
  __syncthreads();

  int k0 = 2*t;
  // P2: u = kc@w0 ; a = gelu(u), up = gelu'(u)
  for (int rg = 0; rg < 4; ++rg){
    float acc[16][2];
    #pragma unroll
    for (int i = 0; i < 16; ++i){ acc[i][0]=0.f; acc[i][1]=0.f; }
    #pragma unroll 2
    for (int d = 0; d < 128; d += 2){
      float2 wA = *(const float2*)(w0 + (size_t)d*HIDN + k0);
      float2 wB = *(const float2*)(w0 + (size_t)(d+1)*HIDN + k0);
      #pragma unroll
      for (int rr = 0; rr < 16; ++rr){
        u32 kp = *(const u32*)&kc_s[(size_t)(rg*16+rr)*DHD + d];
        float klo = bflo(kp), khi = bfhi(kp);
        acc[rr][0] += klo*wA.x + khi*wB.x;
        acc[rr][1] += klo*wA.y + khi*wB.y;
      }
    }
    #pragma unroll
    for (int rr = 0; rr < 16; ++rr){
      int r = rg*16 + rr;
      float u0 = acc[rr][0], u1 = acc[rr][1];
      float cdf0 = 0.5f*(1.f + erff(u0*0.70710678118654752f));
      float cdf1 = 0.5f*(1.f + erff(u1*0.70710678118654752f));
      float up0 = cdf0 + u0*0.3989422804014327f*expf(-0.5f*u0*u0);
      float up1 = cdf1 + u1*0.3989422804014327f*expf(-0.5f*u1*u1);
      *(u32*)&a_s[(size_t)r*HIDN + k0] = pack2(u0*cdf0, u1*cdf1);
      *(u32*)&up_s[(size_t)r*HIDN + k0] = pack2(up0, up1);
    }
  }
  __syncthreads();

  // P3: h = a@w1 ; rowwise rmsnorm fwd+bwd -> dh, dg
  int wv = t >> 6, ln = t & 63;
  {
    float hacc[16][2];
    #pragma unroll
    for (int i = 0; i < 16; ++i){ hacc[i][0]=0.f; hacc[i][1]=0.f; }
    #pragma unroll 2
    for (int k = 0; k < 512; k += 2){
      float w00 = w1[(size_t)k*DHD + ln];
      float w01 = w1[(size_t)k*DHD + ln + 64];
      float w10 = w1[(size_t)(k+1)*DHD + ln];
      float w11 = w1[(size_t)(k+1)*DHD + ln + 64];
      #pragma unroll
      for (int rr = 0; rr < 16; ++rr){
        u32 ap = *(const u32*)&a_s[(size_t)(wv*16+rr)*HIDN + k];
        float alo = bflo(ap), ahi = bfhi(ap);
        hacc[rr][0] += alo*w00 + ahi*w10;
        hacc[rr][1] += alo*w01 + ahi*w11;
      }
    }
    float g0 = g[ln], g1 = g[ln+64];
    float dg0 = 0.f, dg1 = 0.f;
    #pragma unroll 1
    for (int rr = 0; rr < 16; ++rr){
      int r = wv*16 + rr;
      float h0 = hacc[rr][0], h1 = hacc[rr][1];
      float ssq = waveRedSum(h0*h0 + h1*h1);
      float rv = rsqrtf(ssq*(1.f/DHD) + 1e-6f);
      float n0 = h0*rv, n1 = h1*rv;
      float p0 = n0*g0 + kc_g[(size_t)r*DHD + ln];
      float p1 = n1*g1 + kc_g[(size_t)r*DHD + ln + 64];
      float lrv = lr_g[r];
      float dp0 = (2.f/DHD)*lrv*(p0 - vc_g[(size_t)r*DHD + ln]);
      float dp1 = (2.f/DHD)*lrv*(p1 - vc_g[(size_t)r*DHD + ln + 64]);
      dg0 += dp0*n0; dg1 += dp1*n1;
      float dn0 = dp0*g0, dn1 = dp1*g1;
      float dot = waveRedSum(dn0*h0 + dn1*h1);
      float c3 = rv*rv*rv*(1.f/DHD);
      dh_s[(size_t)r*DHD + ln]      = f2bf(rv*dn0 - c3*dot*h0);
      dh_s[(size_t)r*DHD + ln + 64] = f2bf(rv*dn1 - c3*dot*h1);
    }
    atomicAdd(&sg[ln], -dg0);
    atomicAdd(&sg[ln+64], -dg1);
  }
  __syncthreads();

  // P4: s_w1 = -(a^T @ dh)
  {
    int cc0 = 2*(t & 63);
    int tg = t >> 6;
    for (int kb = 0; kb < 16; ++kb){
      int kk0 = (tg + 4*kb)*8;
      float acc[8][2];
      #pragma unroll
      for (int j = 0; j < 8; ++j){ acc[j][0]=0.f; acc[j][1]=0.f; }
      #pragma unroll 2
      for (int r = 0; r < 64; ++r){
        uint4 araw = *(const uint4*)&a_s[(size_t)r*HIDN + kk0];
        u32 dpair = *(const u32*)&dh_s[(size_t)r*DHD + cc0];
        float d0 = bflo(dpair), d1 = bfhi(dpair);
        float av0 = bflo(araw.x), av1 = bfhi(araw.x), av2 = bflo(araw.y), av3 = bfhi(araw.y);
        float av4 = bflo(araw.z), av5 = bfhi(araw.z), av6 = bflo(araw.w), av7 = bfhi(araw.w);
        acc[0][0]+=av0*d0; acc[0][1]+=av0*d1; acc[1][0]+=av1*d0; acc[1][1]+=av1*d1;
        acc[2][0]+=av2*d0; acc[2][1]+=av2*d1; acc[3][0]+=av3*d0; acc[3][1]+=av3*d1;
        acc[4][0]+=av4*d0; acc[4][1]+=av4*d1; acc[5][0]+=av5*d0; acc[5][1]+=av5*d1;
        acc[6][0]+=av6*d0; acc[6][1]+=av6*d1; acc[7][0]+=av7*d0; acc[7][1]+=av7*d1;
      }
      #pragma unroll
      for (int j = 0; j < 8; ++j)
        *(u32*)&sw1[(size_t)(kk0+j)*DHD + cc0] = pack2(-acc[j][0], -acc[j][1]);
    }
  }
  __syncthreads();

  // P5: du = (dh @ w1T) * up  -> overwrite a_s
  {
    for (int rg = 0; rg < 8; ++rg){
      float acc[8][2];
      #pragma unroll
      for (int j = 0; j < 8; ++j){ acc[j][0]=0.f; acc[j][1]=0.f; }
      #pragma unroll 2
      for (int cc = 0; cc < 128; cc += 2){
        float2 wv0 = *(const float2*)(w1t + (size_t)cc*HIDN + k0);
        float2 wv1 = *(const float2*)(w1t + (size_t)(cc+1)*HIDN + k0);
        #pragma unroll
        for (int rr = 0; rr < 8; ++rr){
          u32 dpair = *(const u32*)&dh_s[(size_t)(rg*8+rr)*DHD + cc];
          float d0 = bflo(dpair), d1 = bfhi(dpair);
          acc[rr][0] += d0*wv0.x + d1*wv1.x;
          acc[rr][1] += d0*wv0.y + d1*wv1.y;
        }
      }
      #pragma unroll
      for (int rr = 0; rr < 8; ++rr){
        int r = rg*8 + rr;
        u32 upp = *(const u32*)&up_s[(size_t)r*HIDN + k0];
        *(u32*)&a_s[(size_t)r*HIDN + k0] = pack2(acc[rr][0]*bflo(upp), acc[rr][1]*bfhi(upp));
      }
    }
  }
  __syncthreads();

  // P6: s_w0 = -(kc^T @ du)
  {
    for (int dg = 0; dg < 16; ++dg){
      int d0 = dg*8;
      float acc[8][2];
      #pragma unroll
      for (int j = 0; j < 8; ++j){ acc[j][0]=0.f; acc[j][1]=0.f; }
      #pragma unroll 2
      for (int r = 0; r < 64; ++r){
        uint4 kraw = *(const uint4*)&kc_s[(size_t)r*DHD + d0];
        u32 dupair = *(const u32*)&a_s[(size_t)r*HIDN + k0];
        float u0 = bflo(dupair), u1 = bfhi(dupair);
        float kv0 = bflo(kraw.x), kv1 = bfhi(kraw.x), kv2 = bflo(kraw.y), kv3 = bfhi(kraw.y);
        float kv4 = bflo(kraw.z), kv5 = bfhi(kraw.z), kv6 = bflo(kraw.w), kv7 = bfhi(kraw.w);
        acc[0][0]+=kv0*u0; acc[0][1]+=kv0*u1; acc[1][0]+=kv1*u0; acc[1][1]+=kv1*u1;
        acc[2][0]+=kv2*u0; acc[2][1]+=kv2*u1; acc[3][0]+=kv3*u0; acc[3][1]+=kv3*u1;
        acc[4][0]+=kv4*u0; acc[4][1]+=kv4*u1; acc[5][0]+=kv5*u0; acc[5][1]+=kv5*u1;
        acc[6][0]+=kv6*u0; acc[6][1]+=kv6*u1; acc[7][0]+=kv7*u0; acc[7][1]+=kv7*u1;
      }
      #pragma unroll
      for (int j = 0; j < 8; ++j)
        *(u32*)&sw0[(size_t)(d0+j)*HIDN + k0] = pack2(-acc[j][0], -acc[j][1]);
    }
  }
}

// ---------------- momentum + decay scans (f32 state, bf16 storage) ----------------
__global__ __launch_bounds__(256) void k_scan(
    const float* __restrict__ mw0, const float* __restrict__ mw1, const float* __restrict__ mg,
    const u16* __restrict__ SW0, const u16* __restrict__ SW1, const float* __restrict__ SG,
    const float* __restrict__ momb, const float* __restrict__ decb,
    u16* __restrict__ W0C, u16* __restrict__ W1C, float* __restrict__ GC){
  int bh = blockIdx.y;
  int e = blockIdx.x*256 + threadIdx.x;
  const float* momp = momb + bh*NCH;
  const float* decp = decb + bh*NCH;
  float m = 0.f, W;
  if (e < 65536){
    W = mw0[(size_t)bh*65536 + e];
    const u16* su = SW0 + (size_t)bh*NCH*65536 + e;
    u16* outp = W0C + (size_t)bh*NCH*65536 + e;
    for (int c = 0; c < NCH; ++c){
      outp[(size_t)c*65536] = f2bf(W);
      float sv = bf2f(su[(size_t)c*65536]);
      m = momp[c]*m + sv;
      W = (1.f - decp[c])*W + m;
    }
  } else if (e < 131072){
    int e2 = e - 65536;
    W = mw1[(size_t)bh*65536 + e2];
    const u16* su = SW1 + (size_t)bh*NCH*65536 + e2;
    u16* outp = W1C + (size_t)bh*NCH*65536 + e2;
    for (int c = 0; c < NCH; ++c){
      outp[(size_t)c*65536] = f2bf(W);
      float sv = bf2f(su[(size_t)c*65536]);
      m = momp[c]*m + sv;
      W = (1.f - decp[c])*W + m;
    }
  } else if (e < 131200){
    int e3 = e - 131072;
    W = mg[(size_t)bh*128 + e3];
    const float* su = SG + (size_t)bh*NCH*128 + e3;
    float* outp = GC + (size_t)bh*NCH*128 + e3;
    for (int c = 0; c < NCH; ++c){
      outp[(size_t)c*128] = W;
      float sv = su[(size_t)c*128];
      m = momp[c]*m + sv;
      W = (1.f - decp[c])*W + m;
    }
  }
}

// ---------------- retrieval (forward MLP through per-chunk weights) ----------------
__global__ __launch_bounds__(256) void k_retrieve(
    const float* __restrict__ Q, const u16* __restrict__ W0C, const u16* __restrict__ W1C,
    const float* __restrict__ GC, const float* __restrict__ gate,
    float* __restrict__ OH){
  extern __shared__ char smem[];
  u16* q_s = (u16*)smem;          // [64][128]
  u16* a_s = q_s + 64*128;        // [64][512]
  int c = blockIdx.x, bh = blockIdx.y, t = threadIdx.x;
  size_t bc = (size_t)bh*NCH + c;
  const float* q_g = Q + bc*(CHK*DHD);
  const u16* w0c = W0C + bc*(size_t)(DHD*HIDN);
  const u16* w1c = W1C + bc*(size_t)(HIDN*DHD);
  const float* gc = GC + bc*DHD;

  #pragma unroll
  for (int i = 0; i < 32; ++i){ int idx = t + 256*i; q_s[idx] = f2bf(q_g[idx]); }
  __syncthreads();

  int k0 = 2*t;
  for (int rg = 0; rg < 4; ++rg){
    float acc[16][2];
    #pragma unroll
    for (int i = 0; i < 16; ++i){ acc[i][0]=0.f; acc[i][1]=0.f; }
    #pragma unroll 2
    for (int d = 0; d < 128; d += 2){
      u32 wA = *(const u32*)&w0c[(size_t)d*HIDN + k0];
      u32 wB = *(const u32*)&w0c[(size_t)(d+1)*HIDN + k0];
      float wa0 = bflo(wA), wa1 = bfhi(wA), wb0 = bflo(wB), wb1 = bfhi(wB);
      #pragma unroll
      for (int rr = 0; rr < 16; ++rr){
        u32 qp = *(const u32*)&q_s[(size_t)(rg*16+rr)*DHD + d];
        float qlo = bflo(qp), qhi = bfhi(qp);
        acc[rr][0] += qlo*wa0 + qhi*wb0;
        acc[rr][1] += qlo*wa1 + qhi*wb1;
      }
    }
    #pragma unroll
    for (int rr = 0; rr < 16; ++rr){
      int r = rg*16 + rr;
      float u0 = acc[rr][0], u1 = acc[rr][1];
      float a0v = u0*0.5f*(1.f + erff(u0*0.70710678118654752f));
      float a1v = u1*0.5f*(1.f + erff(u1*0.70710678118654752f));
      *(u32*)&a_s[(size_t)r*HIDN + k0] = pack2(a0v, a1v);
    }
  }
  __syncthreads();

  int wv = t >> 6, ln = t & 63;
  float hacc[16][2];
  #pragma unroll
  for (int i = 0; i < 16; ++i){ hacc[i][0]=0.f; hacc[i][1]=0.f; }
  #pragma unroll 2
  for (int k = 0; k < 512; k += 2){
    float w00 = bf2f(w1c[(size_t)k*DHD + ln]);
    float w01 = bf2f(w1c[(size_t)k*DHD + ln + 64]);
    float w10 = bf2f(w1c[(size_t)(k+1)*DHD + ln]);
    float w11 = bf2f(w1c[(size_t)(k+1)*DHD + ln + 64]);
    #pragma unroll
    for (int rr = 0; rr < 16; ++rr){
      u32 ap = *(const u32*)&a_s[(size_t)(wv*16+rr)*HIDN + k];
      float alo = bflo(ap), ahi = bfhi(ap);
      hacc[rr][0] += alo*w00 + ahi*w10;
      hacc[rr][1] += alo*w01 + ahi*w11;
    }
  }
  float g0 = gc[ln], g1 = gc[ln+64];
  #pragma unroll 1
  for (int rr = 0; rr < 16; ++rr){
    int r = wv*16 + rr;
    float h0 = hacc[rr][0], h1 = hacc[rr][1];
    float ssq = waveRedSum(h0*h0 + h1*h1);
    float rv = rsqrtf(ssq*(1.f/DHD) + 1e-6f);
    float p0 = h0*rv*g0 + q_g[(size_t)r*DHD + ln];
    float p1 = h1*rv*g1 + q_g[(size_t)r*DHD + ln + 64];
    int tok = c*CHK + r;
    float gv = gate[(size_t)tok*8 + bh];
    OH[(size_t)tok*DIMX + bh*DHD + ln]      = p0*gv;
    OH[(size_t)tok*DIMX + bh*DHD + ln + 64] = p1*gv;
  }
}

// ---------------- launch ----------------
extern "C" void kernel_launch(void* const* d_in, const int* in_sizes, int n_in,
                              void* d_out, int out_size, void* d_ws, size_t ws_size,
                              hipStream_t stream) {
  (void)in_sizes; (void)n_in; (void)out_size; (void)ws_size;
  const float* x     = (const float*)d_in[0];
  const float* snw   = (const float*)d_in[1];
  const float* rnw   = (const float*)d_in[2];
  const float* Wq    = (const float*)d_in[3];
  const float* Wk    = (const float*)d_in[4];
  const float* Wv    = (const float*)d_in[5];
  const float* Wstep = (const float*)d_in[6];
  const float* bstep = (const float*)d_in[7];
  const float* Wmom  = (const float*)d_in[8];
  const float* bmom  = (const float*)d_in[9];
  const float* Wdec  = (const float*)d_in[10];
  const float* bdec  = (const float*)d_in[11];
  const float* gateW = (const float*)d_in[12];
  const float* combW = (const float*)d_in[13];
  const float* mw0   = (const float*)d_in[14];
  const float* mw1   = (const float*)d_in[15];
  const float* mg    = (const float*)d_in[16];
  float* out = (float*)d_out;

  float* F = (float*)d_ws;
  float* s_     = F;
  float* r_     = s_ + 2097152;
  float* pooled = r_ + 2097152;
  float* lrc    = pooled + 32768;
  float* momb   = lrc + 16384;
  float* decb   = momb + 256;
  float* gate   = decb + 256;
  float* Qc     = gate + 16384;
  float* Kc     = Qc + 2097152;
  float* Vc     = Kc + 2097152;
  float* w1T    = Vc + 2097152;
  float* OH     = w1T + 524288;
  float* SG     = OH + 2097152;
  float* GC     = SG + 32768;
  u16* SW0 = (u16*)(GC + 32768);
  u16* SW1 = SW0 + (size_t)16777216;
  u16* W0C = SW1 + (size_t)16777216;
  u16* W1C = W0C + (size_t)16777216;

  hipMemsetAsync(SG, 0, 32768*sizeof(float), stream);
  k_rmsnorm<<<2048, 256, 0, stream>>>(x, snw, rnw, s_, r_);
  k_pool<<<dim3(32,4), 256, 0, stream>>>(s_, pooled);
  k_lrgate<<<512, 256, 0, stream>>>(s_, r_, Wstep, bstep, gateW, lrc, gate);
  k_momdec<<<32, 64, 0, stream>>>(pooled, Wmom, bmom, Wdec, bdec, momb, decb);
  k_w1t<<<2048, 256, 0, stream>>>(mw1, w1T);
  k_gemm<<<dim3(32,8), 256, 0, stream>>>(s_, Wk, Kc, 1);
  k_gemm<<<dim3(32,8), 256, 0, stream>>>(s_, Wv, Vc, 1);
  k_gemm<<<dim3(32,8), 256, 0, stream>>>(r_, Wq, Qc, 1);
  hipFuncSetAttribute((const void*)k_grad, hipFuncAttributeMaxDynamicSharedMemorySize, 163840);
  k_grad<<<dim3(32,8), 256, 163840, stream>>>(Kc, Vc, lrc, mw0, mw1, w1T, mg, SW0, SW1, SG);
  k_scan<<<dim3(513,8), 256, 0, stream>>>(mw0, mw1, mg, SW0, SW1, SG, momb, decb, W0C, W1C, GC);
  hipFuncSetAttribute((const void*)k_retrieve, hipFuncAttributeMaxDynamicSharedMemorySize, 81920);
  k_retrieve<<<dim3(32,8), 256, 81920, stream>>>(Qc, W0C, W1C, GC, gate, OH);
  k_gemm<<<dim3(32,8), 256, 0, stream>>>(OH, combW, out, 0);
}

// Round 2
// 405.678 us; speedup vs baseline: 2.8806x; 2.8806x over previous
//
#include <hip/hip_runtime.h>
#include <hip/hip_bf16.h>
#include <math.h>

#define NH   8
#define DHD  128
#define HIDN 512
#define CHK  64
#define NCH  32
#define MB   1048576ull

typedef unsigned short u16;
typedef unsigned int   u32;
typedef short s16x8 __attribute__((ext_vector_type(8)));
typedef float f32x4 __attribute__((ext_vector_type(4)));

#define MFMA(a,b,c) __builtin_amdgcn_mfma_f32_16x16x32_bf16((a),(b),(c),0,0,0)

__device__ __forceinline__ float bf2f(u16 v){ return __uint_as_float(((u32)v) << 16); }
__device__ __forceinline__ u16 f2bf(float f){
  u32 u = __float_as_uint(f);
  u += 0x7fffu + ((u >> 16) & 1u);
  return (u16)(u >> 16);
}
__device__ __forceinline__ u32 pack2(float a, float b){
  return (u32)f2bf(a) | ((u32)f2bf(b) << 16);
}
__device__ __forceinline__ float waveRedSum(float v){
  #pragma unroll
  for (int off = 32; off; off >>= 1) v += __shfl_xor(v, off);
  return v;
}
// XOR swizzle: spread 8 consecutive rows across 16B LDS slots (bank-conflict-free frag reads)
__device__ __forceinline__ int swzb(int row, int colb){ return colb ^ ((row & 7) << 4); }

// ---------------- prep ----------------

__global__ __launch_bounds__(256) void k_rmsnorm(const float* __restrict__ x,
    const float* __restrict__ wst, const float* __restrict__ wrt,
    u16* __restrict__ s_bf, u16* __restrict__ r_bf){
  int row = blockIdx.x, t = threadIdx.x;
  float4 v = ((const float4*)(x + (size_t)row*1024))[t];
  float ss = v.x*v.x + v.y*v.y + v.z*v.z + v.w*v.w;
  ss = waveRedSum(ss);
  __shared__ float red[4];
  int wv = t >> 6, ln = t & 63;
  if (ln == 0) red[wv] = ss;
  __syncthreads();
  float rr = rsqrtf((red[0]+red[1]+red[2]+red[3])*(1.f/1024.f) + 1e-6f);
  float4 a = ((const float4*)wst)[t];
  float4 b = ((const float4*)wrt)[t];
  uint2 so = make_uint2(pack2(v.x*rr*a.x, v.y*rr*a.y), pack2(v.z*rr*a.z, v.w*rr*a.w));
  uint2 ro = make_uint2(pack2(v.x*rr*b.x, v.y*rr*b.y), pack2(v.z*rr*b.z, v.w*rr*b.w));
  *(uint2*)(s_bf + (size_t)row*1024 + t*4) = so;
  *(uint2*)(r_bf + (size_t)row*1024 + t*4) = ro;
}

__global__ __launch_bounds__(256) void k_pool(const u16* __restrict__ s_bf, float* __restrict__ pooled){
  int c = blockIdx.x; int d = blockIdx.y*256 + threadIdx.x;
  float acc = 0.f;
  for (int tt = 0; tt < 64; ++tt) acc += bf2f(s_bf[((size_t)c*64+tt)*1024 + d]);
  pooled[(size_t)c*1024 + d] = acc * (1.f/64.f);
}

__global__ __launch_bounds__(256) void k_lrgate(const u16* __restrict__ s_bf, const u16* __restrict__ r_bf,
    const float* __restrict__ Wstep, const float* __restrict__ bstep,
    const float* __restrict__ gateW,
    float* __restrict__ lrc, float* __restrict__ gate){
  int wv = threadIdx.x >> 6, ln = threadIdx.x & 63;
  int tok = blockIdx.x*4 + wv;
  const u16* srow = s_bf + (size_t)tok*1024;
  const u16* rrow = r_bf + (size_t)tok*1024;
  for (int o = 0; o < 16; ++o){
    int h = o & 7;
    const u16* src = (o < 8) ? srow : rrow;
    const float* W = (o < 8) ? Wstep : gateW;
    float acc = 0.f;
    for (int k = ln; k < 1024; k += 64) acc += bf2f(src[k])*W[(size_t)k*8+h];
    acc = waveRedSum(acc);
    if (ln == 0){
      if (o < 8){
        float v = 1.f/(1.f+expf(-(acc + bstep[h])));
        lrc[((size_t)h*NCH + (tok>>6))*CHK + (tok&63)] = v;
      } else {
        gate[(size_t)tok*8 + h] = 1.f/(1.f+expf(-acc));
      }
    }
  }
}

__global__ __launch_bounds__(64) void k_momdec(const float* __restrict__ pooled,
    const float* __restrict__ Wmom, const float* __restrict__ bmom,
    const float* __restrict__ Wdec, const float* __restrict__ bdec,
    float* __restrict__ momb, float* __restrict__ decb){
  int c = blockIdx.x, ln = threadIdx.x;
  const float* prow = pooled + (size_t)c*1024;
  for (int o = 0; o < 16; ++o){
    int h = o & 7;
    const float* W = (o < 8) ? Wmom : Wdec;
    float acc = 0.f;
    for (int k = ln; k < 1024; k += 64) acc += prow[k]*W[(size_t)k*8+h];
    acc = waveRedSum(acc);
    if (ln == 0){
      float bb = (o < 8) ? bmom[h] : bdec[h];
      float v = 1.f/(1.f+expf(-(acc+bb)));
      if (o < 8) momb[h*NCH + c] = v; else decb[h*NCH + c] = v;
    }
  }
}

// batched transpose f32 -> bf16 : in (b,R,C) -> out (b,C,R)
__global__ __launch_bounds__(256) void k_trf(const float* __restrict__ in, u16* __restrict__ out, int R, int C){
  __shared__ u16 tile[32][34];
  int b = blockIdx.z; int c0 = blockIdx.x*32, r0 = blockIdx.y*32;
  int tx = threadIdx.x & 31, ty = threadIdx.x >> 5;
  const float* ib = in + (size_t)b*R*C;
  u16* ob = out + (size_t)b*R*C;
  #pragma unroll
  for (int k = 0; k < 4; ++k) tile[ty+k*8][tx] = f2bf(ib[(size_t)(r0+ty+k*8)*C + c0+tx]);
  __syncthreads();
  #pragma unroll
  for (int k = 0; k < 4; ++k) ob[(size_t)(c0+ty+k*8)*R + r0+tx] = tile[tx][ty+k*8];
}

// batched transpose bf16 -> bf16
__global__ __launch_bounds__(256) void k_trb(const u16* __restrict__ in, u16* __restrict__ out, int R, int C){
  __shared__ u16 tile[32][34];
  int b = blockIdx.z; int c0 = blockIdx.x*32, r0 = blockIdx.y*32;
  int tx = threadIdx.x & 31, ty = threadIdx.x >> 5;
  const u16* ib = in + (size_t)b*R*C;
  u16* ob = out + (size_t)b*R*C;
  #pragma unroll
  for (int k = 0; k < 4; ++k) tile[ty+k*8][tx] = ib[(size_t)(r0+ty+k*8)*C + c0+tx];
  __syncthreads();
  #pragma unroll
  for (int k = 0; k < 4; ++k) ob[(size_t)(c0+ty+k*8)*R + r0+tx] = tile[tx][ty+k*8];
}

__global__ __launch_bounds__(256) void k_cast(const float* __restrict__ in, u16* __restrict__ out, int n){
  int i = blockIdx.x*256 + threadIdx.x;
  if (i < n) out[i] = f2bf(in[i]);
}

// ---------------- MFMA GEMM: M=2048,N=1024,K=1024, A[M][K] bf16, BT[N][K] bf16 ----------------
// mode 0: C f32 [M][N]; mode 1: C bf16 chunked [h][c][tok][d]
__global__ __launch_bounds__(256) void k_gemm_bf(const u16* __restrict__ A, const u16* __restrict__ BT,
    void* __restrict__ Cp, int mode){
  __shared__ char As[8192];    // [64][64] bf16, rows 128B, swizzled
  __shared__ char Bs[16384];   // [128][64]
  int t = threadIdx.x; int l = t & 63, w = t >> 6, lr16 = l & 15, lg = l >> 4;
  int bm = blockIdx.x*64, bn = blockIdx.y*128;
  f32x4 acc[4][2];
  #pragma unroll
  for (int mt = 0; mt < 4; ++mt)
    #pragma unroll
    for (int nt = 0; nt < 2; ++nt) acc[mt][nt] = (f32x4){0.f,0.f,0.f,0.f};
  for (int k0 = 0; k0 < 1024; k0 += 64){
    #pragma unroll
    for (int i = 0; i < 2; ++i){ int e = (i*256+t)*8; int row = e>>6, col = e&63;
      *(s16x8*)(As + row*128 + swzb(row, col*2)) = *(const s16x8*)(A + (size_t)(bm+row)*1024 + k0 + col); }
    #pragma unroll
    for (int i = 0; i < 4; ++i){ int e = (i*256+t)*8; int row = e>>6, col = e&63;
      *(s16x8*)(Bs + row*128 + swzb(row, col*2)) = *(const s16x8*)(BT + (size_t)(bn+row)*1024 + k0 + col); }
    __syncthreads();
    #pragma unroll
    for (int ks = 0; ks < 2; ++ks){
      s16x8 xa[4];
      #pragma unroll
      for (int mt = 0; mt < 4; ++mt){ int row = mt*16 + lr16;
        xa[mt] = *(const s16x8*)(As + row*128 + swzb(row, (ks*32+lg*8)*2)); }
      #pragma unroll
      for (int nt = 0; nt < 2; ++nt){
        int row = w*32 + nt*16 + lr16;
        s16x8 y = *(const s16x8*)(Bs + row*128 + swzb(row, (ks*32+lg*8)*2));
        #pragma unroll
        for (int mt = 0; mt < 4; ++mt) acc[mt][nt] = MFMA(xa[mt], y, acc[mt][nt]);
      }
    }
    __syncthreads();
  }
  #pragma unroll
  for (int mt = 0; mt < 4; ++mt)
    #pragma unroll
    for (int nt = 0; nt < 2; ++nt)
      #pragma unroll
      for (int j = 0; j < 4; ++j){
        int row = bm + mt*16 + lg*4 + j;
        int coln = bn + w*32 + nt*16 + lr16;
        if (mode == 0) ((float*)Cp)[(size_t)row*1024 + coln] = acc[mt][nt][j];
        else { int cI = row>>6, tok = row&63, h = coln>>7, d = coln&127;
          ((u16*)Cp)[((size_t)(h*32+cI)*64 + tok)*128 + d] = f2bf(acc[mt][nt][j]); }
      }
}

// ---------------- grad A: u=kc@w0, a=gelu(u), h=a@w1, rmsnorm fwd+bwd -> dh, dg ----------------
__global__ __launch_bounds__(256) void k_gradA(
    const u16* __restrict__ Kc, const u16* __restrict__ Vc, const float* __restrict__ lrc,
    const u16* __restrict__ w0T, const u16* __restrict__ w1T, const float* __restrict__ mg,
    u16* __restrict__ a_g, u16* __restrict__ up_g, u16* __restrict__ dh_g, float* __restrict__ SG){
  extern __shared__ char sm[];
  char* kc_s = sm;           // [64][128] bf16 swz (16KB)
  char* a_s  = sm + 16384;   // [64][512] bf16 swz (64KB)
  int c = blockIdx.x, bh = blockIdx.y, t = threadIdx.x;
  size_t bc = (size_t)bh*NCH + c;
  int l = t & 63, w = t >> 6, lr16 = l & 15, lg = l >> 4;

  #pragma unroll
  for (int i = 0; i < 4; ++i){ int e = (i*256+t)*8; int row = e>>7, col = e&127;
    *(s16x8*)(kc_s + row*256 + swzb(row, col*2)) = *(const s16x8*)(Kc + bc*8192 + e); }
  __syncthreads();

  // P2: u = kc @ w0  (X=kc [64][128], Y^T=w0T [512][128])
  s16x8 xk[4];
  { int row = w*16 + lr16;
    #pragma unroll
    for (int k = 0; k < 4; ++k) xk[k] = *(const s16x8*)(kc_s + row*256 + swzb(row, (k*32+lg*8)*2)); }
  const u16* w0Th = w0T + (size_t)bh*65536;
  for (int n0 = 0; n0 < 32; ++n0){
    f32x4 acc = {0.f,0.f,0.f,0.f};
    const u16* yb = w0Th + (size_t)(n0*16 + lr16)*128 + lg*8;
    #pragma unroll
    for (int k = 0; k < 4; ++k) acc = MFMA(xk[k], *(const s16x8*)(yb + k*32), acc);
    int hid = n0*16 + lr16;
    #pragma unroll
    for (int j = 0; j < 4; ++j){
      int tok = w*16 + lg*4 + j;
      float u = acc[j];
      float cdf = 0.5f*(1.f + erff(u*0.70710678118654752f));
      float av = u*cdf;
      float upv = cdf + u*0.3989422804014327f*expf(-0.5f*u*u);
      *(u16*)(a_s + tok*1024 + swzb(tok, hid*2)) = f2bf(av);
      a_g[bc*32768 + (size_t)tok*512 + hid] = f2bf(av);
      up_g[bc*32768 + (size_t)tok*512 + hid] = f2bf(upv);
    }
  }
  __syncthreads();

  // P3: h = a @ w1  (X=a [64][512], Y^T=w1T [128][512])
  s16x8 xa[16];
  { int row = w*16 + lr16;
    #pragma unroll
    for (int k = 0; k < 16; ++k) xa[k] = *(const s16x8*)(a_s + row*1024 + swzb(row, (k*32+lg*8)*2)); }
  const u16* w1Th = w1T + (size_t)bh*65536;
  f32x4 hD[8];
  #pragma unroll
  for (int n0 = 0; n0 < 8; ++n0){
    f32x4 acc = {0.f,0.f,0.f,0.f};
    const u16* yb = w1Th + (size_t)(n0*16 + lr16)*512 + lg*8;
    #pragma unroll
    for (int k = 0; k < 16; ++k) acc = MFMA(xa[k], *(const s16x8*)(yb + k*32), acc);
    hD[n0] = acc;
  }
  // rmsnorm fwd + bwd
  float rv[4], lrv[4], dotv[4];
  #pragma unroll
  for (int j = 0; j < 4; ++j){
    float s = 0.f;
    #pragma unroll
    for (int n0 = 0; n0 < 8; ++n0) s += hD[n0][j]*hD[n0][j];
    s += __shfl_xor(s,1); s += __shfl_xor(s,2); s += __shfl_xor(s,4); s += __shfl_xor(s,8);
    rv[j] = rsqrtf(s*(1.f/128.f) + 1e-6f);
    lrv[j] = lrc[bc*64 + w*16 + lg*4 + j];
    dotv[j] = 0.f;
  }
  float dn[8][4];
  #pragma unroll
  for (int n0 = 0; n0 < 8; ++n0){
    int d = n0*16 + lr16;
    float g0 = mg[(size_t)bh*128 + d];
    float dga = 0.f;
    #pragma unroll
    for (int j = 0; j < 4; ++j){
      int tok = w*16 + lg*4 + j;
      float h = hD[n0][j];
      float nrm = h*rv[j];
      float kcv = bf2f(Kc[bc*8192 + (size_t)tok*128 + d]);
      float vcv = bf2f(Vc[bc*8192 + (size_t)tok*128 + d]);
      float p = nrm*g0 + kcv;
      float dp = (2.f/128.f)*lrv[j]*(p - vcv);
      dga += dp*nrm;
      float dnv = dp*g0;
      dn[n0][j] = dnv;
      dotv[j] += dnv*h;
    }
    dga += __shfl_xor(dga,16); dga += __shfl_xor(dga,32);
    if (lg == 0) atomicAdd(SG + bc*128 + d, -dga);
  }
  #pragma unroll
  for (int j = 0; j < 4; ++j){
    float dd = dotv[j];
    dd += __shfl_xor(dd,1); dd += __shfl_xor(dd,2); dd += __shfl_xor(dd,4); dd += __shfl_xor(dd,8);
    dotv[j] = dd;
  }
  #pragma unroll
  for (int n0 = 0; n0 < 8; ++n0){
    int d = n0*16 + lr16;
    #pragma unroll
    for (int j = 0; j < 4; ++j){
      int tok = w*16 + lg*4 + j;
      float c3 = rv[j]*rv[j]*rv[j]*(1.f/128.f);
      float dhv = rv[j]*dn[n0][j] - c3*dotv[j]*hD[n0][j];
      dh_g[bc*8192 + (size_t)tok*128 + d] = f2bf(dhv);
    }
  }
}

// ---------------- grad B: SW1^T = dh^T@a ; duT = (w1@dh^T).upT ; SW0^T = du^T@kc ----------------
__global__ __launch_bounds__(256) void k_gradB(
    const u16* __restrict__ aT_g, const u16* __restrict__ upT_g, const u16* __restrict__ dh_g,
    const u16* __restrict__ dhT_g, const u16* __restrict__ KcT, const u16* __restrict__ w1bf,
    u16* __restrict__ SW0, u16* __restrict__ SW1){
  extern __shared__ char sm[];
  char* aT  = sm;            // [512][64] swz (64KB)
  char* duT = sm + 65536;    // [512][64] swz (64KB)
  char* dhT = sm + 131072;   // [128][64] swz (16KB)
  int c = blockIdx.x, bh = blockIdx.y, t = threadIdx.x;
  size_t bc = (size_t)bh*NCH + c;
  int l = t & 63, w = t >> 6, lr16 = l & 15, lg = l >> 4;
  #pragma unroll
  for (int i = 0; i < 16; ++i){ int e = (i*256+t)*8; int row = e>>6, tok0 = e&63;
    *(s16x8*)(aT + row*128 + swzb(row, tok0*2)) = *(const s16x8*)(aT_g + bc*32768 + e); }
  #pragma unroll
  for (int i = 0; i < 4; ++i){ int e = (i*256+t)*8; int row = e>>6, tok0 = e&63;
    *(s16x8*)(dhT + row*128 + swzb(row, tok0*2)) = *(const s16x8*)(dhT_g + bc*8192 + e); }
  __syncthreads();
  // B1: SW1 [128][512] = -(dh^T @ a)
  {
    s16x8 xd[2][2];
    #pragma unroll
    for (int mt = 0; mt < 2; ++mt){ int row = (2*w+mt)*16 + lr16;
      #pragma unroll
      for (int k = 0; k < 2; ++k) xd[mt][k] = *(const s16x8*)(dhT + row*128 + swzb(row, (k*32+lg*8)*2)); }
    for (int n0 = 0; n0 < 32; ++n0){
      int rowy = n0*16 + lr16;
      s16x8 y0 = *(const s16x8*)(aT + rowy*128 + swzb(rowy, (lg*8)*2));
      s16x8 y1 = *(const s16x8*)(aT + rowy*128 + swzb(rowy, (32+lg*8)*2));
      #pragma unroll
      for (int mt = 0; mt < 2; ++mt){
        f32x4 acc = {0.f,0.f,0.f,0.f};
        acc = MFMA(xd[mt][0], y0, acc);
        acc = MFMA(xd[mt][1], y1, acc);
        int d0 = (2*w+mt)*16 + lg*4;
        int hid = n0*16 + lr16;
        #pragma unroll
        for (int j = 0; j < 4; ++j)
          SW1[bc*65536 + (size_t)(d0+j)*512 + hid] = f2bf(-acc[j]);
      }
    }
  }
  // B2: duT [512][64] = (w1 @ dh^T) * upT
  {
    s16x8 ydh[4][4];
    #pragma unroll
    for (int n = 0; n < 4; ++n)
      #pragma unroll
      for (int k = 0; k < 4; ++k)
        ydh[n][k] = *(const s16x8*)(dh_g + bc*8192 + (size_t)(n*16+lr16)*128 + k*32 + lg*8);
    const u16* xb0 = w1bf + (size_t)bh*65536;
    for (int mi = 0; mi < 8; ++mi){
      int m0 = (w*8+mi)*16;
      s16x8 xw[4];
      const u16* xb = xb0 + (size_t)(m0+lr16)*128 + lg*8;
      #pragma unroll
      for (int k = 0; k < 4; ++k) xw[k] = *(const s16x8*)(xb + k*32);
      #pragma unroll
      for (int n = 0; n < 4; ++n){
        f32x4 acc = {0.f,0.f,0.f,0.f};
        #pragma unroll
        for (int k = 0; k < 4; ++k) acc = MFMA(xw[k], ydh[n][k], acc);
        int tok = n*16 + lr16;
        #pragma unroll
        for (int j = 0; j < 4; ++j){
          int hid = m0 + lg*4 + j;
          float upv = bf2f(upT_g[bc*32768 + (size_t)hid*64 + tok]);
          *(u16*)(duT + hid*128 + swzb(hid, tok*2)) = f2bf(acc[j]*upv);
        }
      }
    }
  }
  __syncthreads();
  // B3: SW0 [512][128] = -(du^T @ kc)
  {
    s16x8 ykc[8][2];
    #pragma unroll
    for (int n = 0; n < 8; ++n)
      #pragma unroll
      for (int k = 0; k < 2; ++k)
        ykc[n][k] = *(const s16x8*)(KcT + bc*8192 + (size_t)(n*16+lr16)*64 + k*32 + lg*8);
    for (int mi = 0; mi < 8; ++mi){
      int m0 = (w*8+mi)*16;
      int row = m0 + lr16;
      s16x8 x0 = *(const s16x8*)(duT + row*128 + swzb(row, (lg*8)*2));
      s16x8 x1 = *(const s16x8*)(duT + row*128 + swzb(row, (32+lg*8)*2));
      #pragma unroll
      for (int n = 0; n < 8; ++n){
        f32x4 acc = {0.f,0.f,0.f,0.f};
        acc = MFMA(x0, ykc[n][0], acc);
        acc = MFMA(x1, ykc[n][1], acc);
        #pragma unroll
        for (int j = 0; j < 4; ++j)
          SW0[bc*65536 + (size_t)(m0+lg*4+j)*128 + n*16+lr16] = f2bf(-acc[j]);
      }
    }
  }
}

// ---------------- scans (f32 state, bf16 storage; init from transposed bf16 weights) ----------------
__global__ __launch_bounds__(256) void k_scan(
    const u16* __restrict__ w0T, const u16* __restrict__ w1T, const float* __restrict__ mg,
    const u16* __restrict__ SW0, const u16* __restrict__ SW1, const float* __restrict__ SG,
    const float* __restrict__ momb, const float* __restrict__ decb,
    u16* __restrict__ W0C, u16* __restrict__ W1C, float* __restrict__ GC){
  int bh = blockIdx.y;
  int e = blockIdx.x*256 + threadIdx.x;
  const float* momp = momb + bh*NCH;
  const float* decp = decb + bh*NCH;
  float m = 0.f, Wv;
  if (e < 65536){
    Wv = bf2f(w0T[(size_t)bh*65536 + e]);
    const u16* su = SW0 + (size_t)bh*NCH*65536 + e;
    u16* outp = W0C + (size_t)bh*NCH*65536 + e;
    for (int c = 0; c < NCH; ++c){
      outp[(size_t)c*65536] = f2bf(Wv);
      m = momp[c]*m + bf2f(su[(size_t)c*65536]);
      Wv = (1.f - decp[c])*Wv + m;
    }
  } else if (e < 131072){
    int e2 = e - 65536;
    Wv = bf2f(w1T[(size_t)bh*65536 + e2]);
    const u16* su = SW1 + (size_t)bh*NCH*65536 + e2;
    u16* outp = W1C + (size_t)bh*NCH*65536 + e2;
    for (int c = 0; c < NCH; ++c){
      outp[(size_t)c*65536] = f2bf(Wv);
      m = momp[c]*m + bf2f(su[(size_t)c*65536]);
      Wv = (1.f - decp[c])*Wv + m;
    }
  } else if (e < 131200){
    int e3 = e - 131072;
    Wv = mg[(size_t)bh*128 + e3];
    const float* su = SG + (size_t)bh*NCH*128 + e3;
    float* outp = GC + (size_t)bh*NCH*128 + e3;
    for (int c = 0; c < NCH; ++c){
      outp[(size_t)c*128] = Wv;
      m = momp[c]*m + su[(size_t)c*128];
      Wv = (1.f - decp[c])*Wv + m;
    }
  }
}

// ---------------- retrieval ----------------
__global__ __launch_bounds__(256) void k_retr(
    const u16* __restrict__ Qc, const u16* __restrict__ W0C, const u16* __restrict__ W1C,
    const float* __restrict__ GC, const float* __restrict__ gate, u16* __restrict__ OH){
  extern __shared__ char sm[];
  char* q_s = sm;           // [64][128] swz (16KB)
  char* a_s = sm + 16384;   // [64][512] swz (64KB)
  int c = blockIdx.x, bh = blockIdx.y, t = threadIdx.x;
  size_t bc = (size_t)bh*NCH + c;
  int l = t & 63, w = t >> 6, lr16 = l & 15, lg = l >> 4;
  #pragma unroll
  for (int i = 0; i < 4; ++i){ int e = (i*256+t)*8; int row = e>>7, col = e&127;
    *(s16x8*)(q_s + row*256 + swzb(row, col*2)) = *(const s16x8*)(Qc + bc*8192 + e); }
  __syncthreads();
  s16x8 xq[4];
  { int row = w*16 + lr16;
    #pragma unroll
    for (int k = 0; k < 4; ++k) xq[k] = *(const s16x8*)(q_s + row*256 + swzb(row, (k*32+lg*8)*2)); }
  const u16* w0c = W0C + bc*65536;
  for (int n0 = 0; n0 < 32; ++n0){
    f32x4 acc = {0.f,0.f,0.f,0.f};
    const u16* yb = w0c + (size_t)(n0*16 + lr16)*128 + lg*8;
    #pragma unroll
    for (int k = 0; k < 4; ++k) acc = MFMA(xq[k], *(const s16x8*)(yb + k*32), acc);
    int hid = n0*16 + lr16;
    #pragma unroll
    for (int j = 0; j < 4; ++j){
      int tok = w*16 + lg*4 + j;
      float u = acc[j];
      float av = u*0.5f*(1.f + erff(u*0.70710678118654752f));
      *(u16*)(a_s + tok*1024 + swzb(tok, hid*2)) = f2bf(av);
    }
  }
  __syncthreads();
  s16x8 xa[16];
  { int row = w*16 + lr16;
    #pragma unroll
    for (int k = 0; k < 16; ++k) xa[k] = *(const s16x8*)(a_s + row*1024 + swzb(row, (k*32+lg*8)*2)); }
  const u16* w1c = W1C + bc*65536;
  f32x4 hD[8];
  #pragma unroll
  for (int n0 = 0; n0 < 8; ++n0){
    f32x4 acc = {0.f,0.f,0.f,0.f};
    const u16* yb = w1c + (size_t)(n0*16 + lr16)*512 + lg*8;
    #pragma unroll
    for (int k = 0; k < 16; ++k) acc = MFMA(xa[k], *(const s16x8*)(yb + k*32), acc);
    hD[n0] = acc;
  }
  float rv[4];
  #pragma unroll
  for (int j = 0; j < 4; ++j){
    float s = 0.f;
    #pragma unroll
    for (int n0 = 0; n0 < 8; ++n0) s += hD[n0][j]*hD[n0][j];
    s += __shfl_xor(s,1); s += __shfl_xor(s,2); s += __shfl_xor(s,4); s += __shfl_xor(s,8);
    rv[j] = rsqrtf(s*(1.f/128.f) + 1e-6f);
  }
  float gtv[4];
  #pragma unroll
  for (int j = 0; j < 4; ++j){ int tokg = c*64 + w*16 + lg*4 + j; gtv[j] = gate[(size_t)tokg*8 + bh]; }
  #pragma unroll
  for (int n0 = 0; n0 < 8; ++n0){
    int d = n0*16 + lr16;
    float g0 = GC[bc*128 + d];
    #pragma unroll
    for (int j = 0; j < 4; ++j){
      int tok = w*16 + lg*4 + j; int tokg = c*64 + tok;
      float qv = bf2f(Qc[bc*8192 + (size_t)tok*128 + d]);
      float p = hD[n0][j]*rv[j]*g0 + qv;
      OH[(size_t)tokg*1024 + bh*128 + d] = f2bf(p*gtv[j]);
    }
  }
}

// ---------------- launch ----------------
extern "C" void kernel_launch(void* const* d_in, const int* in_sizes, int n_in,
                              void* d_out, int out_size, void* d_ws, size_t ws_size,
                              hipStream_t stream) {
  (void)in_sizes; (void)n_in; (void)out_size; (void)ws_size;
  const float* x     = (const float*)d_in[0];
  const float* snw   = (const float*)d_in[1];
  const float* rnw   = (const float*)d_in[2];
  const float* Wq    = (const float*)d_in[3];
  const float* Wk    = (const float*)d_in[4];
  const float* Wv    = (const float*)d_in[5];
  const float* Wstep = (const float*)d_in[6];
  const float* bstep = (const float*)d_in[7];
  const float* Wmom  = (const float*)d_in[8];
  const float* bmom  = (const float*)d_in[9];
  const float* Wdec  = (const float*)d_in[10];
  const float* bdec  = (const float*)d_in[11];
  const float* gateW = (const float*)d_in[12];
  const float* combW = (const float*)d_in[13];
  const float* mw0   = (const float*)d_in[14];
  const float* mw1   = (const float*)d_in[15];
  const float* mg    = (const float*)d_in[16];
  float* out = (float*)d_out;

  char* Wb = (char*)d_ws;
  u16* Qc    = (u16*)(Wb + 0*MB);
  u16* Kc    = (u16*)(Wb + 4*MB);
  u16* Vc    = (u16*)(Wb + 8*MB);
  u16* KcT   = (u16*)(Wb + 12*MB);
  u16* s_bf  = (u16*)(Wb + 16*MB);
  u16* r_bf  = (u16*)(Wb + 20*MB);
  u16* WqT   = (u16*)(Wb + 24*MB);
  u16* WkT   = (u16*)(Wb + 26*MB);
  u16* WvT   = (u16*)(Wb + 28*MB);
  u16* combT = (u16*)(Wb + 30*MB);
  u16* w0T   = (u16*)(Wb + 32*MB);
  u16* w1T   = (u16*)(Wb + 33*MB);
  u16* w1bf  = (u16*)(Wb + 34*MB);
  u16* SW0   = (u16*)(Wb + 35*MB);
  u16* SW1   = (u16*)(Wb + 67*MB);
  u16* OH    = (u16*)(Wb + 99*MB);
  float* pooled = (float*)(Wb + 103*MB);
  float* lrc    = (float*)(Wb + 103*MB + 131072);
  float* momb   = (float*)(Wb + 103*MB + 196608);
  float* decb   = (float*)(Wb + 103*MB + 197632);
  float* gate   = (float*)(Wb + 103*MB + 198656);
  float* SG     = (float*)(Wb + 103*MB + 264192);
  float* GC     = (float*)(Wb + 103*MB + 395264);
  // region X (dead after k_gradB) aliased by W0C/W1C (written by k_scan)
  u16* a_g   = (u16*)(Wb + 104*MB);
  u16* up_g  = (u16*)(Wb + 120*MB);
  u16* aT_g  = (u16*)(Wb + 136*MB);
  u16* upT_g = (u16*)(Wb + 152*MB);
  u16* dh_g  = (u16*)(Wb + 168*MB);
  u16* dhT_g = (u16*)(Wb + 172*MB);
  u16* W0C   = (u16*)(Wb + 104*MB);
  u16* W1C   = (u16*)(Wb + 136*MB);

  hipFuncSetAttribute((const void*)k_gradA, hipFuncAttributeMaxDynamicSharedMemorySize, 81920);
  hipFuncSetAttribute((const void*)k_gradB, hipFuncAttributeMaxDynamicSharedMemorySize, 147456);
  hipFuncSetAttribute((const void*)k_retr,  hipFuncAttributeMaxDynamicSharedMemorySize, 81920);

  hipMemsetAsync(SG, 0, 131072, stream);
  k_rmsnorm<<<2048, 256, 0, stream>>>(x, snw, rnw, s_bf, r_bf);
  k_pool<<<dim3(32,4), 256, 0, stream>>>(s_bf, pooled);
  k_lrgate<<<512, 256, 0, stream>>>(s_bf, r_bf, Wstep, bstep, gateW, lrc, gate);
  k_momdec<<<32, 64, 0, stream>>>(pooled, Wmom, bmom, Wdec, bdec, momb, decb);
  k_trf<<<dim3(32,32,1), 256, 0, stream>>>(Wq, WqT, 1024, 1024);
  k_trf<<<dim3(32,32,1), 256, 0, stream>>>(Wk, WkT, 1024, 1024);
  k_trf<<<dim3(32,32,1), 256, 0, stream>>>(Wv, WvT, 1024, 1024);
  k_trf<<<dim3(32,32,1), 256, 0, stream>>>(combW, combT, 1024, 1024);
  k_trf<<<dim3(16,4,8), 256, 0, stream>>>(mw0, w0T, 128, 512);
  k_trf<<<dim3(4,16,8), 256, 0, stream>>>(mw1, w1T, 512, 128);
  k_cast<<<2048, 256, 0, stream>>>(mw1, w1bf, 524288);
  k_gemm_bf<<<dim3(32,8), 256, 0, stream>>>(s_bf, WkT, (void*)Kc, 1);
  k_gemm_bf<<<dim3(32,8), 256, 0, stream>>>(s_bf, WvT, (void*)Vc, 1);
  k_gemm_bf<<<dim3(32,8), 256, 0, stream>>>(r_bf, WqT, (void*)Qc, 1);
  k_trb<<<dim3(4,2,256), 256, 0, stream>>>(Kc, KcT, 64, 128);
  k_gradA<<<dim3(32,8), 256, 81920, stream>>>(Kc, Vc, lrc, w0T, w1T, mg, a_g, up_g, dh_g, SG);
  k_trb<<<dim3(16,2,256), 256, 0, stream>>>(a_g, aT_g, 64, 512);
  k_trb<<<dim3(16,2,256), 256, 0, stream>>>(up_g, upT_g, 64, 512);
  k_trb<<<dim3(4,2,256), 256, 0, stream>>>(dh_g, dhT_g, 64, 128);
  k_gradB<<<dim3(32,8), 256, 147456, stream>>>(aT_g, upT_g, dh_g, dhT_g, KcT, w1bf, SW0, SW1);
  k_scan<<<dim3(513,8), 256, 0, stream>>>(w0T, w1T, mg, SW0, SW1, SG, momb, decb, W0C, W1C, GC);
  k_retr<<<dim3(32,8), 256, 81920, stream>>>(Qc, W0C, W1C, GC, gate, OH);
  k_gemm_bf<<<dim3(32,8), 256, 0, stream>>>(OH, combT, (void*)out, 0);
}

// Round 3
// 311.400 us; speedup vs baseline: 3.7527x; 1.3028x over previous
//
#include <hip/hip_runtime.h>
#include <hip/hip_bf16.h>
#include <math.h>

#define NH   8
#define DHD  128
#define HIDN 512
#define CHK  64
#define NCH  32
#define MB   1048576ull

typedef unsigned short u16;
typedef unsigned int   u32;
typedef short s16x8 __attribute__((ext_vector_type(8)));
typedef float f32x4 __attribute__((ext_vector_type(4)));

#define MFMA(a,b,c) __builtin_amdgcn_mfma_f32_16x16x32_bf16((a),(b),(c),0,0,0)

__device__ __forceinline__ float bf2f(u16 v){ return __uint_as_float(((u32)v) << 16); }
__device__ __forceinline__ u16 f2bf(float f){
  u32 u = __float_as_uint(f);
  u += 0x7fffu + ((u >> 16) & 1u);
  return (u16)(u >> 16);
}
__device__ __forceinline__ u32 pack2(float a, float b){
  return (u32)f2bf(a) | ((u32)f2bf(b) << 16);
}
__device__ __forceinline__ float waveRedSum(float v){
  #pragma unroll
  for (int off = 32; off; off >>= 1) v += __shfl_xor(v, off);
  return v;
}
// XOR swizzle: spread rows across 16B LDS slots (bank-conflict-free frag reads)
__device__ __forceinline__ int swzb(int row, int colb){ return colb ^ ((row & 7) << 4); }

// ---------------- prep ----------------

__global__ __launch_bounds__(256) void k_rmsnorm(const float* __restrict__ x,
    const float* __restrict__ wst, const float* __restrict__ wrt,
    u16* __restrict__ s_bf, u16* __restrict__ r_bf){
  int row = blockIdx.x, t = threadIdx.x;
  float4 v = ((const float4*)(x + (size_t)row*1024))[t];
  float ss = v.x*v.x + v.y*v.y + v.z*v.z + v.w*v.w;
  ss = waveRedSum(ss);
  __shared__ float red[4];
  int wv = t >> 6, ln = t & 63;
  if (ln == 0) red[wv] = ss;
  __syncthreads();
  float rr = rsqrtf((red[0]+red[1]+red[2]+red[3])*(1.f/1024.f) + 1e-6f);
  float4 a = ((const float4*)wst)[t];
  float4 b = ((const float4*)wrt)[t];
  uint2 so = make_uint2(pack2(v.x*rr*a.x, v.y*rr*a.y), pack2(v.z*rr*a.z, v.w*rr*a.w));
  uint2 ro = make_uint2(pack2(v.x*rr*b.x, v.y*rr*b.y), pack2(v.z*rr*b.z, v.w*rr*b.w));
  *(uint2*)(s_bf + (size_t)row*1024 + t*4) = so;
  *(uint2*)(r_bf + (size_t)row*1024 + t*4) = ro;
}

__global__ __launch_bounds__(256) void k_pool(const u16* __restrict__ s_bf, float* __restrict__ pooled){
  int c = blockIdx.x; int d = blockIdx.y*256 + threadIdx.x;
  float acc = 0.f;
  for (int tt = 0; tt < 64; ++tt) acc += bf2f(s_bf[((size_t)c*64+tt)*1024 + d]);
  pooled[(size_t)c*1024 + d] = acc * (1.f/64.f);
}

__global__ __launch_bounds__(256) void k_lrgate(const u16* __restrict__ s_bf, const u16* __restrict__ r_bf,
    const float* __restrict__ Wstep, const float* __restrict__ bstep,
    const float* __restrict__ gateW,
    float* __restrict__ lrc, float* __restrict__ gate){
  int wv = threadIdx.x >> 6, ln = threadIdx.x & 63;
  int tok = blockIdx.x*4 + wv;
  const u16* srow = s_bf + (size_t)tok*1024;
  const u16* rrow = r_bf + (size_t)tok*1024;
  for (int o = 0; o < 16; ++o){
    int h = o & 7;
    const u16* src = (o < 8) ? srow : rrow;
    const float* W = (o < 8) ? Wstep : gateW;
    float acc = 0.f;
    for (int k = ln; k < 1024; k += 64) acc += bf2f(src[k])*W[(size_t)k*8+h];
    acc = waveRedSum(acc);
    if (ln == 0){
      if (o < 8){
        float v = 1.f/(1.f+expf(-(acc + bstep[h])));
        lrc[((size_t)h*NCH + (tok>>6))*CHK + (tok&63)] = v;
      } else {
        gate[(size_t)tok*8 + h] = 1.f/(1.f+expf(-acc));
      }
    }
  }
}

__global__ __launch_bounds__(64) void k_momdec(const float* __restrict__ pooled,
    const float* __restrict__ Wmom, const float* __restrict__ bmom,
    const float* __restrict__ Wdec, const float* __restrict__ bdec,
    float* __restrict__ momb, float* __restrict__ decb){
  int c = blockIdx.x, ln = threadIdx.x;
  const float* prow = pooled + (size_t)c*1024;
  for (int o = 0; o < 16; ++o){
    int h = o & 7;
    const float* W = (o < 8) ? Wmom : Wdec;
    float acc = 0.f;
    for (int k = ln; k < 1024; k += 64) acc += prow[k]*W[(size_t)k*8+h];
    acc = waveRedSum(acc);
    if (ln == 0){
      float bb = (o < 8) ? bmom[h] : bdec[h];
      float v = 1.f/(1.f+expf(-(acc+bb)));
      if (o < 8) momb[h*NCH + c] = v; else decb[h*NCH + c] = v;
    }
  }
}

// batched transpose f32 -> bf16 : in (b,R,C) -> out (b,C,R)
__global__ __launch_bounds__(256) void k_trf(const float* __restrict__ in, u16* __restrict__ out, int R, int C){
  __shared__ u16 tile[32][34];
  int b = blockIdx.z; int c0 = blockIdx.x*32, r0 = blockIdx.y*32;
  int tx = threadIdx.x & 31, ty = threadIdx.x >> 5;
  const float* ib = in + (size_t)b*R*C;
  u16* ob = out + (size_t)b*R*C;
  #pragma unroll
  for (int k = 0; k < 4; ++k) tile[ty+k*8][tx] = f2bf(ib[(size_t)(r0+ty+k*8)*C + c0+tx]);
  __syncthreads();
  #pragma unroll
  for (int k = 0; k < 4; ++k) ob[(size_t)(c0+ty+k*8)*R + r0+tx] = tile[tx][ty+k*8];
}

__global__ __launch_bounds__(256) void k_cast(const float* __restrict__ in, u16* __restrict__ out, int n){
  int i = blockIdx.x*256 + threadIdx.x;
  if (i < n) out[i] = f2bf(in[i]);
}

// ---------------- MFMA GEMM: M=2048,N=1024,K=1024, A[M][K] bf16, BT[N][K] bf16 ----------------
// 64x64 tile, grid (32,16), 4 waves. mode 0: C f32 [M][N]; mode 1: C bf16 chunked [h][c][tok][d]
__global__ __launch_bounds__(256) void k_gemm_bf(const u16* __restrict__ A, const u16* __restrict__ BT,
    void* __restrict__ Cp, int mode){
  __shared__ char As[8192];
  __shared__ char Bs[8192];
  int t = threadIdx.x; int l = t & 63, w = t >> 6, lr16 = l & 15, lg = l >> 4;
  int bm = blockIdx.x*64, bn = blockIdx.y*64;
  f32x4 acc[4];
  #pragma unroll
  for (int mt = 0; mt < 4; ++mt) acc[mt] = (f32x4){0.f,0.f,0.f,0.f};
  for (int k0 = 0; k0 < 1024; k0 += 64){
    #pragma unroll
    for (int i = 0; i < 2; ++i){ int e = (i*256+t)*8; int row = e>>6, col = e&63;
      *(s16x8*)(As + row*128 + swzb(row, col*2)) = *(const s16x8*)(A + (size_t)(bm+row)*1024 + k0 + col);
      *(s16x8*)(Bs + row*128 + swzb(row, col*2)) = *(const s16x8*)(BT + (size_t)(bn+row)*1024 + k0 + col); }
    __syncthreads();
    #pragma unroll
    for (int ks = 0; ks < 2; ++ks){
      int rowb = w*16 + lr16;
      s16x8 y = *(const s16x8*)(Bs + rowb*128 + swzb(rowb, (ks*32+lg*8)*2));
      #pragma unroll
      for (int mt = 0; mt < 4; ++mt){ int row = mt*16 + lr16;
        s16x8 xa = *(const s16x8*)(As + row*128 + swzb(row, (ks*32+lg*8)*2));
        acc[mt] = MFMA(xa, y, acc[mt]); }
    }
    __syncthreads();
  }
  #pragma unroll
  for (int mt = 0; mt < 4; ++mt)
    #pragma unroll
    for (int j = 0; j < 4; ++j){
      int row = bm + mt*16 + lg*4 + j;
      int coln = bn + w*16 + lr16;
      if (mode == 0) ((float*)Cp)[(size_t)row*1024 + coln] = acc[mt][j];
      else { int cI = row>>6, tok = row&63, h = coln>>7, d = coln&127;
        ((u16*)Cp)[((size_t)(h*32+cI)*64 + tok)*128 + d] = f2bf(acc[mt][j]); }
    }
}

// ---------------- fused gradient: fwd MLP + rmsnorm bwd + all three outer products ----------------
// 512 threads (8 waves). wave w: tg = w&3 (token group), dhf = w>>2 (d-half / hid-half).
__global__ __launch_bounds__(512) void k_grad(
    const u16* __restrict__ Kc, const u16* __restrict__ Vc, const float* __restrict__ lrc,
    const u16* __restrict__ w0T, const u16* __restrict__ w1T, const u16* __restrict__ w1bf,
    const float* __restrict__ mg,
    u16* __restrict__ SW0, u16* __restrict__ SW1, float* __restrict__ SG){
  extern __shared__ char sm[];
  char* a_s  = sm;            // [64][512] bf16 swz rows 1KB; later duT [512][64] rows 128B
  char* up_s = sm + 65536;    // [64][512] bf16 swz
  char* dh_s = sm + 131072;   // [64][128] bf16 swz rows 256B (scratch before dh written)
  float* scr = (float*)dh_s;  // ssq[0..127], dot[128..255], dga[256..767]

  int c = blockIdx.x, bh = blockIdx.y, t = threadIdx.x;
  size_t bc = (size_t)bh*NCH + c;
  int l = t & 63, w = t >> 6, lr16 = l & 15, lg = l >> 4;
  int tg = w & 3, dhf = w >> 2;

  const u16* kc_g = Kc + bc*8192;
  const u16* vc_g = Vc + bc*8192;

  // ---- P2: u = kc @ w0, a = gelu(u), up = gelu'(u) ----
  s16x8 xk[4];
  #pragma unroll
  for (int k = 0; k < 4; ++k)
    xk[k] = *(const s16x8*)(kc_g + (size_t)(tg*16+lr16)*128 + k*32 + lg*8);
  const u16* w0Th = w0T + (size_t)bh*65536;
  for (int n0h = 0; n0h < 16; ++n0h){
    int n0 = dhf*16 + n0h;
    f32x4 acc = {0.f,0.f,0.f,0.f};
    const u16* yb = w0Th + (size_t)(n0*16 + lr16)*128 + lg*8;
    #pragma unroll
    for (int k = 0; k < 4; ++k) acc = MFMA(xk[k], *(const s16x8*)(yb + k*32), acc);
    int hid = n0*16 + lr16;
    #pragma unroll
    for (int j = 0; j < 4; ++j){
      int tok = tg*16 + lg*4 + j;
      float u = acc[j];
      float cdf = 0.5f*(1.f + erff(u*0.70710678118654752f));
      float av = u*cdf;
      float upv = cdf + u*0.3989422804014327f*expf(-0.5f*u*u);
      *(u16*)(a_s + tok*1024 + swzb(tok, hid*2)) = f2bf(av);
      *(u16*)(up_s + tok*1024 + swzb(tok, hid*2)) = f2bf(upv);
    }
  }
  __syncthreads();

  // ---- P3: h = a @ w1 (wave: toks tg, d range dhf*64..+63), rmsnorm fwd+bwd ----
  s16x8 xa[16];
  #pragma unroll
  for (int k = 0; k < 16; ++k){ int row = tg*16 + lr16;
    xa[k] = *(const s16x8*)(a_s + row*1024 + swzb(row, (k*32+lg*8)*2)); }
  const u16* w1Th = w1T + (size_t)bh*65536;
  f32x4 hD[4];
  #pragma unroll
  for (int n0l = 0; n0l < 4; ++n0l){
    int d = dhf*64 + n0l*16 + lr16;
    f32x4 acc = {0.f,0.f,0.f,0.f};
    const u16* yb = w1Th + (size_t)d*512 + lg*8;
    #pragma unroll
    for (int k = 0; k < 16; ++k) acc = MFMA(xa[k], *(const s16x8*)(yb + k*32), acc);
    hD[n0l] = acc;
  }
  // per-token ssq partial over this wave's 64 d
  #pragma unroll
  for (int j = 0; j < 4; ++j){
    float s = 0.f;
    #pragma unroll
    for (int n0l = 0; n0l < 4; ++n0l) s += hD[n0l][j]*hD[n0l][j];
    s += __shfl_xor(s,1); s += __shfl_xor(s,2); s += __shfl_xor(s,4); s += __shfl_xor(s,8);
    if (lr16 == 0) scr[dhf*64 + tg*16 + lg*4 + j] = s;
  }
  __syncthreads();
  float rv[4], lrv[4], dotp[4];
  #pragma unroll
  for (int j = 0; j < 4; ++j){
    int tok = tg*16 + lg*4 + j;
    float tot = scr[tok] + scr[64 + tok];
    rv[j] = rsqrtf(tot*(1.f/128.f) + 1e-6f);
    lrv[j] = lrc[bc*64 + tok];
    dotp[j] = 0.f;
  }
  float dn[4][4];
  #pragma unroll
  for (int n0l = 0; n0l < 4; ++n0l){
    int d = dhf*64 + n0l*16 + lr16;
    float g0 = mg[(size_t)bh*128 + d];
    float dgav = 0.f;
    #pragma unroll
    for (int j = 0; j < 4; ++j){
      int tok = tg*16 + lg*4 + j;
      float h = hD[n0l][j];
      float nrm = h*rv[j];
      float kcv = bf2f(kc_g[(size_t)tok*128 + d]);
      float vcv = bf2f(vc_g[(size_t)tok*128 + d]);
      float p = nrm*g0 + kcv;
      float dp = (2.f/128.f)*lrv[j]*(p - vcv);
      dgav += dp*nrm;
      float dnv = dp*g0;
      dn[n0l][j] = dnv;
      dotp[j] += dnv*h;
    }
    dgav += __shfl_xor(dgav,16); dgav += __shfl_xor(dgav,32);
    if (lg == 0) scr[256 + w*64 + n0l*16 + lr16] = dgav;
  }
  #pragma unroll
  for (int j = 0; j < 4; ++j){
    float dd = dotp[j];
    dd += __shfl_xor(dd,1); dd += __shfl_xor(dd,2); dd += __shfl_xor(dd,4); dd += __shfl_xor(dd,8);
    if (lr16 == 0) scr[128 + dhf*64 + tg*16 + lg*4 + j] = dd;
  }
  __syncthreads();
  float dotv[4];
  #pragma unroll
  for (int j = 0; j < 4; ++j){
    int tok = tg*16 + lg*4 + j;
    dotv[j] = scr[128 + tok] + scr[128 + 64 + tok];
  }
  if (t < 128){
    int dh2 = t >> 6, dl = t & 63;
    float s = scr[256 + (dh2*4+0)*64 + dl] + scr[256 + (dh2*4+1)*64 + dl]
            + scr[256 + (dh2*4+2)*64 + dl] + scr[256 + (dh2*4+3)*64 + dl];
    SG[bc*128 + t] = -s;
  }
  __syncthreads();   // scratch fully consumed
  #pragma unroll
  for (int n0l = 0; n0l < 4; ++n0l){
    int d = dhf*64 + n0l*16 + lr16;
    #pragma unroll
    for (int j = 0; j < 4; ++j){
      int tok = tg*16 + lg*4 + j;
      float c3 = rv[j]*rv[j]*rv[j]*(1.f/128.f);
      float dhv = rv[j]*dn[n0l][j] - c3*dotv[j]*hD[n0l][j];
      *(u16*)(dh_s + tok*256 + swzb(tok, d*2)) = f2bf(dhv);
    }
  }
  __syncthreads();

  // ---- B1: SW1[128 d][512 hid] = -(dh^T @ a). wave: all 128 d, hid range w*64..+63 ----
  {
    s16x8 yB[4][2];
    #pragma unroll
    for (int n0l = 0; n0l < 4; ++n0l){
      int hid = w*64 + n0l*16 + lr16;
      #pragma unroll
      for (int ks = 0; ks < 2; ++ks){
        s16x8 v;
        #pragma unroll
        for (int e = 0; e < 8; ++e){ int tok = ks*32 + lg*8 + e;
          v[e] = *(const short*)(a_s + tok*1024 + swzb(tok, hid*2)); }
        yB[n0l][ks] = v;
      }
    }
    #pragma unroll 2
    for (int mt = 0; mt < 8; ++mt){
      int d = mt*16 + lr16;
      s16x8 xD[2];
      #pragma unroll
      for (int ks = 0; ks < 2; ++ks){
        s16x8 v;
        #pragma unroll
        for (int e = 0; e < 8; ++e){ int tok = ks*32 + lg*8 + e;
          v[e] = *(const short*)(dh_s + tok*256 + swzb(tok, d*2)); }
        xD[ks] = v;
      }
      #pragma unroll
      for (int n0l = 0; n0l < 4; ++n0l){
        f32x4 acc = {0.f,0.f,0.f,0.f};
        acc = MFMA(xD[0], yB[n0l][0], acc);
        acc = MFMA(xD[1], yB[n0l][1], acc);
        int hid = w*64 + n0l*16 + lr16;
        #pragma unroll
        for (int j = 0; j < 4; ++j)
          SW1[bc*65536 + (size_t)(mt*16 + lg*4 + j)*512 + hid] = f2bf(-acc[j]);
      }
    }
  }
  __syncthreads();   // a_s reads done; safe to overwrite with duT

  // ---- B2: duT[512 hid][64 tok] = (w1 @ dh^T) * up^T  -> stored into a_s region ----
  {
    s16x8 yD[4][4];
    #pragma unroll
    for (int n = 0; n < 4; ++n){
      int tok = n*16 + lr16;
      #pragma unroll
      for (int k = 0; k < 4; ++k)
        yD[n][k] = *(const s16x8*)(dh_s + tok*256 + swzb(tok, (k*32+lg*8)*2));
    }
    const u16* w1b = w1bf + (size_t)bh*65536;
    #pragma unroll 2
    for (int mi = 0; mi < 4; ++mi){
      int m0 = w*64 + mi*16;
      s16x8 xw[4];
      #pragma unroll
      for (int k = 0; k < 4; ++k)
        xw[k] = *(const s16x8*)(w1b + (size_t)(m0+lr16)*128 + k*32 + lg*8);
      #pragma unroll
      for (int n = 0; n < 4; ++n){
        f32x4 acc = {0.f,0.f,0.f,0.f};
        #pragma unroll
        for (int k = 0; k < 4; ++k) acc = MFMA(xw[k], yD[n][k], acc);
        int tok = n*16 + lr16;
        #pragma unroll
        for (int j = 0; j < 4; ++j){
          int hid = m0 + lg*4 + j;
          float upv = bf2f(*(const u16*)(up_s + tok*1024 + swzb(tok, hid*2)));
          *(u16*)(a_s + hid*128 + swzb(hid, tok*2)) = f2bf(acc[j]*upv);
        }
      }
    }
  }
  __syncthreads();

  // ---- B3: SW0[512 hid][128 d] = -(duT @ kc). wave: hid range w*64..+63, all 128 d ----
  {
    s16x8 yK[8][2];
    #pragma unroll
    for (int n0 = 0; n0 < 8; ++n0){
      int d = n0*16 + lr16;
      #pragma unroll
      for (int ks = 0; ks < 2; ++ks){
        s16x8 v;
        #pragma unroll
        for (int e = 0; e < 8; ++e){ int tok = ks*32 + lg*8 + e;
          v[e] = *(const short*)&kc_g[(size_t)tok*128 + d]; }
        yK[n0][ks] = v;
      }
    }
    #pragma unroll 2
    for (int mi = 0; mi < 4; ++mi){
      int m0 = w*64 + mi*16;
      s16x8 xU[2];
      #pragma unroll
      for (int ks = 0; ks < 2; ++ks){
        int hid = m0 + lr16;
        xU[ks] = *(const s16x8*)(a_s + hid*128 + swzb(hid, (ks*32+lg*8)*2));
      }
      #pragma unroll
      for (int n0 = 0; n0 < 8; ++n0){
        f32x4 acc = {0.f,0.f,0.f,0.f};
        acc = MFMA(xU[0], yK[n0][0], acc);
        acc = MFMA(xU[1], yK[n0][1], acc);
        #pragma unroll
        for (int j = 0; j < 4; ++j)
          SW0[bc*65536 + (size_t)(m0 + lg*4 + j)*128 + n0*16 + lr16] = f2bf(-acc[j]);
      }
    }
  }
}

// ---------------- scans (f32 state, bf16 storage; init from transposed bf16 weights) ----------------
__global__ __launch_bounds__(256) void k_scan(
    const u16* __restrict__ w0T, const u16* __restrict__ w1T, const float* __restrict__ mg,
    const u16* __restrict__ SW0, const u16* __restrict__ SW1, const float* __restrict__ SG,
    const float* __restrict__ momb, const float* __restrict__ decb,
    u16* __restrict__ W0C, u16* __restrict__ W1C, float* __restrict__ GC){
  int bh = blockIdx.y;
  int e = blockIdx.x*256 + threadIdx.x;
  const float* momp = momb + bh*NCH;
  const float* decp = decb + bh*NCH;
  float m = 0.f, Wv;
  if (e < 65536){
    Wv = bf2f(w0T[(size_t)bh*65536 + e]);
    const u16* su = SW0 + (size_t)bh*NCH*65536 + e;
    u16* outp = W0C + (size_t)bh*NCH*65536 + e;
    for (int c = 0; c < NCH; ++c){
      outp[(size_t)c*65536] = f2bf(Wv);
      m = momp[c]*m + bf2f(su[(size_t)c*65536]);
      Wv = (1.f - decp[c])*Wv + m;
    }
  } else if (e < 131072){
    int e2 = e - 65536;
    Wv = bf2f(w1T[(size_t)bh*65536 + e2]);
    const u16* su = SW1 + (size_t)bh*NCH*65536 + e2;
    u16* outp = W1C + (size_t)bh*NCH*65536 + e2;
    for (int c = 0; c < NCH; ++c){
      outp[(size_t)c*65536] = f2bf(Wv);
      m = momp[c]*m + bf2f(su[(size_t)c*65536]);
      Wv = (1.f - decp[c])*Wv + m;
    }
  } else if (e < 131200){
    int e3 = e - 131072;
    Wv = mg[(size_t)bh*128 + e3];
    const float* su = SG + (size_t)bh*NCH*128 + e3;
    float* outp = GC + (size_t)bh*NCH*128 + e3;
    for (int c = 0; c < NCH; ++c){
      outp[(size_t)c*128] = Wv;
      m = momp[c]*m + su[(size_t)c*128];
      Wv = (1.f - decp[c])*Wv + m;
    }
  }
}

// ---------------- retrieval (512 threads, 8 waves) ----------------
__global__ __launch_bounds__(512) void k_retr(
    const u16* __restrict__ Qc, const u16* __restrict__ W0C, const u16* __restrict__ W1C,
    const float* __restrict__ GC, const float* __restrict__ gate, u16* __restrict__ OH){
  extern __shared__ char sm[];
  char* a_s = sm;                      // [64][512] swz
  float* scr = (float*)(sm + 65536);   // [128]
  int c = blockIdx.x, bh = blockIdx.y, t = threadIdx.x;
  size_t bc = (size_t)bh*NCH + c;
  int l = t & 63, w = t >> 6, lr16 = l & 15, lg = l >> 4;
  int tg = w & 3, dhf = w >> 2;
  const u16* q_g = Qc + bc*8192;

  s16x8 xq[4];
  #pragma unroll
  for (int k = 0; k < 4; ++k)
    xq[k] = *(const s16x8*)(q_g + (size_t)(tg*16+lr16)*128 + k*32 + lg*8);
  const u16* w0c = W0C + bc*65536;
  for (int n0h = 0; n0h < 16; ++n0h){
    int n0 = dhf*16 + n0h;
    f32x4 acc = {0.f,0.f,0.f,0.f};
    const u16* yb = w0c + (size_t)(n0*16 + lr16)*128 + lg*8;
    #pragma unroll
    for (int k = 0; k < 4; ++k) acc = MFMA(xq[k], *(const s16x8*)(yb + k*32), acc);
    int hid = n0*16 + lr16;
    #pragma unroll
    for (int j = 0; j < 4; ++j){
      int tok = tg*16 + lg*4 + j;
      float u = acc[j];
      float av = u*0.5f*(1.f + erff(u*0.70710678118654752f));
      *(u16*)(a_s + tok*1024 + swzb(tok, hid*2)) = f2bf(av);
    }
  }
  __syncthreads();
  s16x8 xa[16];
  #pragma unroll
  for (int k = 0; k < 16; ++k){ int row = tg*16 + lr16;
    xa[k] = *(const s16x8*)(a_s + row*1024 + swzb(row, (k*32+lg*8)*2)); }
  const u16* w1c = W1C + bc*65536;
  f32x4 hD[4];
  #pragma unroll
  for (int n0l = 0; n0l < 4; ++n0l){
    int d = dhf*64 + n0l*16 + lr16;
    f32x4 acc = {0.f,0.f,0.f,0.f};
    const u16* yb = w1c + (size_t)d*512 + lg*8;
    #pragma unroll
    for (int k = 0; k < 16; ++k) acc = MFMA(xa[k], *(const s16x8*)(yb + k*32), acc);
    hD[n0l] = acc;
  }
  #pragma unroll
  for (int j = 0; j < 4; ++j){
    float s = 0.f;
    #pragma unroll
    for (int n0l = 0; n0l < 4; ++n0l) s += hD[n0l][j]*hD[n0l][j];
    s += __shfl_xor(s,1); s += __shfl_xor(s,2); s += __shfl_xor(s,4); s += __shfl_xor(s,8);
    if (lr16 == 0) scr[dhf*64 + tg*16 + lg*4 + j] = s;
  }
  __syncthreads();
  float rv[4], gtv[4];
  #pragma unroll
  for (int j = 0; j < 4; ++j){
    int tok = tg*16 + lg*4 + j;
    rv[j] = rsqrtf((scr[tok] + scr[64 + tok])*(1.f/128.f) + 1e-6f);
    gtv[j] = gate[(size_t)(c*64 + tok)*8 + bh];
  }
  #pragma unroll
  for (int n0l = 0; n0l < 4; ++n0l){
    int d = dhf*64 + n0l*16 + lr16;
    float g0 = GC[bc*128 + d];
    #pragma unroll
    for (int j = 0; j < 4; ++j){
      int tok = tg*16 + lg*4 + j; int tokg = c*64 + tok;
      float qv = bf2f(q_g[(size_t)tok*128 + d]);
      float p = hD[n0l][j]*rv[j]*g0 + qv;
      OH[(size_t)tokg*1024 + bh*128 + d] = f2bf(p*gtv[j]);
    }
  }
}

// ---------------- launch ----------------
extern "C" void kernel_launch(void* const* d_in, const int* in_sizes, int n_in,
                              void* d_out, int out_size, void* d_ws, size_t ws_size,
                              hipStream_t stream) {
  (void)in_sizes; (void)n_in; (void)out_size; (void)ws_size;
  const float* x     = (const float*)d_in[0];
  const float* snw   = (const float*)d_in[1];
  const float* rnw   = (const float*)d_in[2];
  const float* Wq    = (const float*)d_in[3];
  const float* Wk    = (const float*)d_in[4];
  const float* Wv    = (const float*)d_in[5];
  const float* Wstep = (const float*)d_in[6];
  const float* bstep = (const float*)d_in[7];
  const float* Wmom  = (const float*)d_in[8];
  const float* bmom  = (const float*)d_in[9];
  const float* Wdec  = (const float*)d_in[10];
  const float* bdec  = (const float*)d_in[11];
  const float* gateW = (const float*)d_in[12];
  const float* combW = (const float*)d_in[13];
  const float* mw0   = (const float*)d_in[14];
  const float* mw1   = (const float*)d_in[15];
  const float* mg    = (const float*)d_in[16];
  float* out = (float*)d_out;

  char* Wb = (char*)d_ws;
  u16* Qc    = (u16*)(Wb + 0*MB);
  u16* Kc    = (u16*)(Wb + 4*MB);
  u16* Vc    = (u16*)(Wb + 8*MB);
  u16* s_bf  = (u16*)(Wb + 12*MB);
  u16* r_bf  = (u16*)(Wb + 16*MB);
  u16* WqT   = (u16*)(Wb + 20*MB);
  u16* WkT   = (u16*)(Wb + 22*MB);
  u16* WvT   = (u16*)(Wb + 24*MB);
  u16* combT = (u16*)(Wb + 26*MB);
  u16* w0T   = (u16*)(Wb + 28*MB);
  u16* w1T   = (u16*)(Wb + 29*MB);
  u16* w1bf  = (u16*)(Wb + 30*MB);
  u16* OH    = (u16*)(Wb + 31*MB);
  u16* SW0   = (u16*)(Wb + 35*MB);
  u16* SW1   = (u16*)(Wb + 67*MB);
  u16* W0C   = (u16*)(Wb + 99*MB);
  u16* W1C   = (u16*)(Wb + 131*MB);
  float* pooled = (float*)(Wb + 163*MB);
  float* lrc    = (float*)(Wb + 163*MB + 131072);
  float* momb   = (float*)(Wb + 163*MB + 196608);
  float* decb   = (float*)(Wb + 163*MB + 197632);
  float* gate   = (float*)(Wb + 163*MB + 198656);
  float* SG     = (float*)(Wb + 163*MB + 264192);
  float* GC     = (float*)(Wb + 163*MB + 395264);

  hipFuncSetAttribute((const void*)k_grad, hipFuncAttributeMaxDynamicSharedMemorySize, 147456);
  hipFuncSetAttribute((const void*)k_retr, hipFuncAttributeMaxDynamicSharedMemorySize, 66560);

  k_rmsnorm<<<2048, 256, 0, stream>>>(x, snw, rnw, s_bf, r_bf);
  k_pool<<<dim3(32,4), 256, 0, stream>>>(s_bf, pooled);
  k_lrgate<<<512, 256, 0, stream>>>(s_bf, r_bf, Wstep, bstep, gateW, lrc, gate);
  k_momdec<<<32, 64, 0, stream>>>(pooled, Wmom, bmom, Wdec, bdec, momb, decb);
  k_trf<<<dim3(32,32,1), 256, 0, stream>>>(Wq, WqT, 1024, 1024);
  k_trf<<<dim3(32,32,1), 256, 0, stream>>>(Wk, WkT, 1024, 1024);
  k_trf<<<dim3(32,32,1), 256, 0, stream>>>(Wv, WvT, 1024, 1024);
  k_trf<<<dim3(32,32,1), 256, 0, stream>>>(combW, combT, 1024, 1024);
  k_trf<<<dim3(16,4,8), 256, 0, stream>>>(mw0, w0T, 128, 512);
  k_trf<<<dim3(4,16,8), 256, 0, stream>>>(mw1, w1T, 512, 128);
  k_cast<<<2048, 256, 0, stream>>>(mw1, w1bf, 524288);
  k_gemm_bf<<<dim3(32,16), 256, 0, stream>>>(s_bf, WkT, (void*)Kc, 1);
  k_gemm_bf<<<dim3(32,16), 256, 0, stream>>>(s_bf, WvT, (void*)Vc, 1);
  k_gemm_bf<<<dim3(32,16), 256, 0, stream>>>(r_bf, WqT, (void*)Qc, 1);
  k_grad<<<dim3(32,8), 512, 147456, stream>>>(Kc, Vc, lrc, w0T, w1T, w1bf, mg, SW0, SW1, SG);
  k_scan<<<dim3(513,8), 256, 0, stream>>>(w0T, w1T, mg, SW0, SW1, SG, momb, decb, W0C, W1C, GC);
  k_retr<<<dim3(32,8), 512, 66560, stream>>>(Qc, W0C, W1C, GC, gate, OH);
  k_gemm_bf<<<dim3(32,16), 256, 0, stream>>>(OH, combT, (void*)out, 0);
}

// Round 4
// 304.180 us; speedup vs baseline: 3.8417x; 1.0237x over previous
//
#include <hip/hip_runtime.h>
#include <hip/hip_bf16.h>
#include <math.h>

#define NH   8
#define DHD  128
#define HIDN 512
#define CHK  64
#define NCH  32
#define MB   1048576ull

typedef unsigned short u16;
typedef unsigned int   u32;
typedef short s16x8 __attribute__((ext_vector_type(8)));
typedef float f32x4 __attribute__((ext_vector_type(4)));

#define MFMA(a,b,c) __builtin_amdgcn_mfma_f32_16x16x32_bf16((a),(b),(c),0,0,0)

__device__ __forceinline__ float bf2f(u16 v){ return __uint_as_float(((u32)v) << 16); }
__device__ __forceinline__ u16 f2bf(float f){
  u32 u = __float_as_uint(f);
  u += 0x7fffu + ((u >> 16) & 1u);
  return (u16)(u >> 16);
}
__device__ __forceinline__ u32 pack2(float a, float b){
  return (u32)f2bf(a) | ((u32)f2bf(b) << 16);
}
__device__ __forceinline__ float waveRedSum(float v){
  #pragma unroll
  for (int off = 32; off; off >>= 1) v += __shfl_xor(v, off);
  return v;
}
// swizzles: 16B-slot XOR within a row-stripe (bank-conflict-free frag reads)
__device__ __forceinline__ int swzb(int row, int colb){ return colb ^ ((row & 7) << 4); }
// for the [64][1024B] a-tile: also spread row-bit3,4 into byte-bits 5,6 so
// column gathers (tok varying by 8 via lg) hit distinct bank octets
__device__ __forceinline__ int swza(int row, int colb){
  return colb ^ ((row & 7) << 4) ^ (((row >> 3) & 3) << 5);
}

// ---------------- prep ----------------

__global__ __launch_bounds__(256) void k_rmsnorm(const float* __restrict__ x,
    const float* __restrict__ wst, const float* __restrict__ wrt,
    u16* __restrict__ s_bf, u16* __restrict__ r_bf){
  int row = blockIdx.x, t = threadIdx.x;
  float4 v = ((const float4*)(x + (size_t)row*1024))[t];
  float ss = v.x*v.x + v.y*v.y + v.z*v.z + v.w*v.w;
  ss = waveRedSum(ss);
  __shared__ float red[4];
  int wv = t >> 6, ln = t & 63;
  if (ln == 0) red[wv] = ss;
  __syncthreads();
  float rr = rsqrtf((red[0]+red[1]+red[2]+red[3])*(1.f/1024.f) + 1e-6f);
  float4 a = ((const float4*)wst)[t];
  float4 b = ((const float4*)wrt)[t];
  uint2 so = make_uint2(pack2(v.x*rr*a.x, v.y*rr*a.y), pack2(v.z*rr*a.z, v.w*rr*a.w));
  uint2 ro = make_uint2(pack2(v.x*rr*b.x, v.y*rr*b.y), pack2(v.z*rr*b.z, v.w*rr*b.w));
  *(uint2*)(s_bf + (size_t)row*1024 + t*4) = so;
  *(uint2*)(r_bf + (size_t)row*1024 + t*4) = ro;
}

__global__ __launch_bounds__(256) void k_pool(const u16* __restrict__ s_bf, float* __restrict__ pooled){
  int c = blockIdx.x; int d = blockIdx.y*256 + threadIdx.x;
  float acc = 0.f;
  for (int tt = 0; tt < 64; ++tt) acc += bf2f(s_bf[((size_t)c*64+tt)*1024 + d]);
  pooled[(size_t)c*1024 + d] = acc * (1.f/64.f);
}

__global__ __launch_bounds__(256) void k_lrgate(const u16* __restrict__ s_bf, const u16* __restrict__ r_bf,
    const float* __restrict__ Wstep, const float* __restrict__ bstep,
    const float* __restrict__ gateW,
    float* __restrict__ lrc, float* __restrict__ gate){
  int wv = threadIdx.x >> 6, ln = threadIdx.x & 63;
  int tok = blockIdx.x*4 + wv;
  const u16* srow = s_bf + (size_t)tok*1024;
  const u16* rrow = r_bf + (size_t)tok*1024;
  for (int o = 0; o < 16; ++o){
    int h = o & 7;
    const u16* src = (o < 8) ? srow : rrow;
    const float* W = (o < 8) ? Wstep : gateW;
    float acc = 0.f;
    for (int k = ln; k < 1024; k += 64) acc += bf2f(src[k])*W[(size_t)k*8+h];
    acc = waveRedSum(acc);
    if (ln == 0){
      if (o < 8){
        float v = 1.f/(1.f+expf(-(acc + bstep[h])));
        lrc[((size_t)h*NCH + (tok>>6))*CHK + (tok&63)] = v;
      } else {
        gate[(size_t)tok*8 + h] = 1.f/(1.f+expf(-acc));
      }
    }
  }
}

__global__ __launch_bounds__(64) void k_momdec(const float* __restrict__ pooled,
    const float* __restrict__ Wmom, const float* __restrict__ bmom,
    const float* __restrict__ Wdec, const float* __restrict__ bdec,
    float* __restrict__ momb, float* __restrict__ decb){
  int c = blockIdx.x, ln = threadIdx.x;
  const float* prow = pooled + (size_t)c*1024;
  for (int o = 0; o < 16; ++o){
    int h = o & 7;
    const float* W = (o < 8) ? Wmom : Wdec;
    float acc = 0.f;
    for (int k = ln; k < 1024; k += 64) acc += prow[k]*W[(size_t)k*8+h];
    acc = waveRedSum(acc);
    if (ln == 0){
      float bb = (o < 8) ? bmom[h] : bdec[h];
      float v = 1.f/(1.f+expf(-(acc+bb)));
      if (o < 8) momb[h*NCH + c] = v; else decb[h*NCH + c] = v;
    }
  }
}

// batched transpose f32 -> bf16 : in (b,R,C) -> out (b,C,R)
__global__ __launch_bounds__(256) void k_trf(const float* __restrict__ in, u16* __restrict__ out, int R, int C){
  __shared__ u16 tile[32][34];
  int b = blockIdx.z; int c0 = blockIdx.x*32, r0 = blockIdx.y*32;
  int tx = threadIdx.x & 31, ty = threadIdx.x >> 5;
  const float* ib = in + (size_t)b*R*C;
  u16* ob = out + (size_t)b*R*C;
  #pragma unroll
  for (int k = 0; k < 4; ++k) tile[ty+k*8][tx] = f2bf(ib[(size_t)(r0+ty+k*8)*C + c0+tx]);
  __syncthreads();
  #pragma unroll
  for (int k = 0; k < 4; ++k) ob[(size_t)(c0+ty+k*8)*R + r0+tx] = tile[tx][ty+k*8];
}

// 4 fused 1024x1024 f32->bf16 transposes (z picks matrix)
__global__ __launch_bounds__(256) void k_trf4(
    const float* __restrict__ A0, const float* __restrict__ A1,
    const float* __restrict__ A2, const float* __restrict__ A3,
    u16* __restrict__ O0, u16* __restrict__ O1, u16* __restrict__ O2, u16* __restrict__ O3){
  __shared__ u16 tile[32][34];
  int z = blockIdx.z;
  const float* in = (z==0)?A0:(z==1)?A1:(z==2)?A2:A3;
  u16* out = (z==0)?O0:(z==1)?O1:(z==2)?O2:O3;
  int c0 = blockIdx.x*32, r0 = blockIdx.y*32;
  int tx = threadIdx.x & 31, ty = threadIdx.x >> 5;
  #pragma unroll
  for (int k = 0; k < 4; ++k) tile[ty+k*8][tx] = f2bf(in[(size_t)(r0+ty+k*8)*1024 + c0+tx]);
  __syncthreads();
  #pragma unroll
  for (int k = 0; k < 4; ++k) out[(size_t)(c0+ty+k*8)*1024 + r0+tx] = tile[tx][ty+k*8];
}

__global__ __launch_bounds__(256) void k_cast(const float* __restrict__ in, u16* __restrict__ out, int n){
  int i = blockIdx.x*256 + threadIdx.x;
  if (i < n) out[i] = f2bf(in[i]);
}

// ---------------- MFMA GEMM body: M=2048,N=1024,K=1024, A[M][K] bf16, BT[N][K] bf16 ----------------
// 64x64 tile, 4 waves. mode 0: C f32 [M][N]; mode 1: C bf16 chunked [h][c][tok][d]
__device__ __forceinline__ void gemm_body(const u16* __restrict__ A, const u16* __restrict__ BT,
    void* __restrict__ Cp, int mode){
  __shared__ char As[8192];
  __shared__ char Bs[8192];
  int t = threadIdx.x; int l = t & 63, w = t >> 6, lr16 = l & 15, lg = l >> 4;
  int bm = blockIdx.x*64, bn = blockIdx.y*64;
  f32x4 acc[4];
  #pragma unroll
  for (int mt = 0; mt < 4; ++mt) acc[mt] = (f32x4){0.f,0.f,0.f,0.f};
  for (int k0 = 0; k0 < 1024; k0 += 64){
    #pragma unroll
    for (int i = 0; i < 2; ++i){ int e = (i*256+t)*8; int row = e>>6, col = e&63;
      *(s16x8*)(As + row*128 + swzb(row, col*2)) = *(const s16x8*)(A + (size_t)(bm+row)*1024 + k0 + col);
      *(s16x8*)(Bs + row*128 + swzb(row, col*2)) = *(const s16x8*)(BT + (size_t)(bn+row)*1024 + k0 + col); }
    __syncthreads();
    #pragma unroll
    for (int ks = 0; ks < 2; ++ks){
      int rowb = w*16 + lr16;
      s16x8 y = *(const s16x8*)(Bs + rowb*128 + swzb(rowb, (ks*32+lg*8)*2));
      #pragma unroll
      for (int mt = 0; mt < 4; ++mt){ int row = mt*16 + lr16;
        s16x8 xa = *(const s16x8*)(As + row*128 + swzb(row, (ks*32+lg*8)*2));
        acc[mt] = MFMA(xa, y, acc[mt]); }
    }
    __syncthreads();
  }
  #pragma unroll
  for (int mt = 0; mt < 4; ++mt)
    #pragma unroll
    for (int j = 0; j < 4; ++j){
      int row = bm + mt*16 + lg*4 + j;
      int coln = bn + w*16 + lr16;
      if (mode == 0) ((float*)Cp)[(size_t)row*1024 + coln] = acc[mt][j];
      else { int cI = row>>6, tok = row&63, h = coln>>7, d = coln&127;
        ((u16*)Cp)[((size_t)(h*32+cI)*64 + tok)*128 + d] = f2bf(acc[mt][j]); }
    }
}

__global__ __launch_bounds__(256) void k_gemm_bf(const u16* __restrict__ A, const u16* __restrict__ BT,
    void* __restrict__ Cp, int mode){ gemm_body(A, BT, Cp, mode); }

// fused QKV: z=0 K, z=1 V, z=2 Q
__global__ __launch_bounds__(256) void k_gemm3(
    const u16* __restrict__ s_bf, const u16* __restrict__ r_bf,
    const u16* __restrict__ WkT, const u16* __restrict__ WvT, const u16* __restrict__ WqT,
    u16* __restrict__ Kc, u16* __restrict__ Vc, u16* __restrict__ Qc){
  int z = blockIdx.z;
  const u16* A = (z==2) ? r_bf : s_bf;
  const u16* BT = (z==0) ? WkT : (z==1) ? WvT : WqT;
  u16* C = (z==0) ? Kc : (z==1) ? Vc : Qc;
  gemm_body(A, BT, (void*)C, 1);
}

// ---------------- fused gradient ----------------
// 512 threads (8 waves). wave w: tg = w&3 (token group), dhf = w>>2 (d-half / hid-half).
// LDS (160KB): a[64][512] swza (->duT[512][64] swzb) | upT[512][64] swzb (->kcT[128][64] swzb)
//            | dh[64][128] swzb rows 256B (scr first 3KB) | dhT[128][64] swzb
__global__ __launch_bounds__(512) void k_grad(
    const u16* __restrict__ Kc, const u16* __restrict__ Vc, const float* __restrict__ lrc,
    const u16* __restrict__ w0T, const u16* __restrict__ w1T, const u16* __restrict__ w1bf,
    const float* __restrict__ mg,
    u16* __restrict__ SW0, u16* __restrict__ SW1, float* __restrict__ SG){
  extern __shared__ char sm[];
  char* a_s   = sm;            // 64KB
  char* upT_s = sm + 65536;    // 64KB
  char* dh_s  = sm + 131072;   // 16KB
  char* dhT_s = sm + 147456;   // 16KB
  char* duT_s = a_s;           // alias after B1
  char* kcT_s = upT_s;         // alias after B2
  float* scr  = (float*)dh_s;  // ssq[0..127], dot[128..255], dga[256..767]

  int c = blockIdx.x, bh = blockIdx.y, t = threadIdx.x;
  size_t bc = (size_t)bh*NCH + c;
  int l = t & 63, w = t >> 6, lr16 = l & 15, lg = l >> 4;
  int tg = w & 3, dhf = w >> 2;

  const u16* kc_g = Kc + bc*8192;
  const u16* vc_g = Vc + bc*8192;

  // ---- P2: u = kc @ w0 ; a = gelu(u) -> a_s ; gelu'(u) -> upT_s ----
  s16x8 xk[4];
  #pragma unroll
  for (int k = 0; k < 4; ++k)
    xk[k] = *(const s16x8*)(kc_g + (size_t)(tg*16+lr16)*128 + k*32 + lg*8);
  const u16* w0Th = w0T + (size_t)bh*65536;
  int tok0 = tg*16 + lg*4;
  for (int n0h = 0; n0h < 16; ++n0h){
    int n0 = dhf*16 + n0h;
    f32x4 acc = {0.f,0.f,0.f,0.f};
    const u16* yb = w0Th + (size_t)(n0*16 + lr16)*128 + lg*8;
    #pragma unroll
    for (int k = 0; k < 4; ++k) acc = MFMA(xk[k], *(const s16x8*)(yb + k*32), acc);
    int hid = n0*16 + lr16;
    float upv[4];
    #pragma unroll
    for (int j = 0; j < 4; ++j){
      int tok = tok0 + j;
      float u = acc[j];
      float cdf = 0.5f*(1.f + erff(u*0.70710678118654752f));
      upv[j] = cdf + u*0.3989422804014327f*expf(-0.5f*u*u);
      *(u16*)(a_s + tok*1024 + swza(tok, hid*2)) = f2bf(u*cdf);
    }
    *(uint2*)(upT_s + hid*128 + swzb(hid, tok0*2)) =
        make_uint2(pack2(upv[0], upv[1]), pack2(upv[2], upv[3]));
  }
  __syncthreads();

  // ---- P3: h = a @ w1 (toks tg, d range dhf*64..+63), rmsnorm fwd+bwd ----
  s16x8 xa[16];
  #pragma unroll
  for (int k = 0; k < 16; ++k){ int row = tg*16 + lr16;
    xa[k] = *(const s16x8*)(a_s + row*1024 + swza(row, (k*32+lg*8)*2)); }
  const u16* w1Th = w1T + (size_t)bh*65536;
  f32x4 hD[4];
  #pragma unroll
  for (int n0l = 0; n0l < 4; ++n0l){
    int d = dhf*64 + n0l*16 + lr16;
    f32x4 acc = {0.f,0.f,0.f,0.f};
    const u16* yb = w1Th + (size_t)d*512 + lg*8;
    #pragma unroll
    for (int k = 0; k < 16; ++k) acc = MFMA(xa[k], *(const s16x8*)(yb + k*32), acc);
    hD[n0l] = acc;
  }
  #pragma unroll
  for (int j = 0; j < 4; ++j){
    float s = 0.f;
    #pragma unroll
    for (int n0l = 0; n0l < 4; ++n0l) s += hD[n0l][j]*hD[n0l][j];
    s += __shfl_xor(s,1); s += __shfl_xor(s,2); s += __shfl_xor(s,4); s += __shfl_xor(s,8);
    if (lr16 == 0) scr[dhf*64 + tg*16 + lg*4 + j] = s;
  }
  __syncthreads();
  float rv[4], lrv[4], dotp[4];
  #pragma unroll
  for (int j = 0; j < 4; ++j){
    int tok = tg*16 + lg*4 + j;
    float tot = scr[tok] + scr[64 + tok];
    rv[j] = rsqrtf(tot*(1.f/128.f) + 1e-6f);
    lrv[j] = lrc[bc*64 + tok];
    dotp[j] = 0.f;
  }
  float dn[4][4];
  #pragma unroll
  for (int n0l = 0; n0l < 4; ++n0l){
    int d = dhf*64 + n0l*16 + lr16;
    float g0 = mg[(size_t)bh*128 + d];
    float dgav = 0.f;
    #pragma unroll
    for (int j = 0; j < 4; ++j){
      int tok = tg*16 + lg*4 + j;
      float h = hD[n0l][j];
      float nrm = h*rv[j];
      float kcv = bf2f(kc_g[(size_t)tok*128 + d]);
      float vcv = bf2f(vc_g[(size_t)tok*128 + d]);
      float p = nrm*g0 + kcv;
      float dp = (2.f/128.f)*lrv[j]*(p - vcv);
      dgav += dp*nrm;
      float dnv = dp*g0;
      dn[n0l][j] = dnv;
      dotp[j] += dnv*h;
    }
    dgav += __shfl_xor(dgav,16); dgav += __shfl_xor(dgav,32);
    if (lg == 0) scr[256 + w*64 + n0l*16 + lr16] = dgav;
  }
  #pragma unroll
  for (int j = 0; j < 4; ++j){
    float dd = dotp[j];
    dd += __shfl_xor(dd,1); dd += __shfl_xor(dd,2); dd += __shfl_xor(dd,4); dd += __shfl_xor(dd,8);
    if (lr16 == 0) scr[128 + dhf*64 + tg*16 + lg*4 + j] = dd;
  }
  __syncthreads();
  float dotv[4];
  #pragma unroll
  for (int j = 0; j < 4; ++j){
    int tok = tg*16 + lg*4 + j;
    dotv[j] = scr[128 + tok] + scr[128 + 64 + tok];
  }
  if (t < 128){
    int dh2 = t >> 6, dl = t & 63;
    float s = scr[256 + (dh2*4+0)*64 + dl] + scr[256 + (dh2*4+1)*64 + dl]
            + scr[256 + (dh2*4+2)*64 + dl] + scr[256 + (dh2*4+3)*64 + dl];
    SG[bc*128 + t] = -s;
  }
  __syncthreads();   // scratch fully consumed; dh region now writable
  #pragma unroll
  for (int n0l = 0; n0l < 4; ++n0l){
    int d = dhf*64 + n0l*16 + lr16;
    float dhv[4];
    #pragma unroll
    for (int j = 0; j < 4; ++j){
      int tok = tg*16 + lg*4 + j;
      float c3 = rv[j]*rv[j]*rv[j]*(1.f/128.f);
      dhv[j] = rv[j]*dn[n0l][j] - c3*dotv[j]*hD[n0l][j];
      *(u16*)(dh_s + tok*256 + swzb(tok, d*2)) = f2bf(dhv[j]);
    }
    *(uint2*)(dhT_s + d*128 + swzb(d, tok0*2)) =
        make_uint2(pack2(dhv[0], dhv[1]), pack2(dhv[2], dhv[3]));
  }
  __syncthreads();

  // ---- B1: SW1[128 d][512 hid] = -(dh^T @ a). A=dhT rows (b128), B=a columns (gather) ----
  {
    s16x8 xD[8][2];
    #pragma unroll
    for (int mt = 0; mt < 8; ++mt){ int row = mt*16 + lr16;
      #pragma unroll
      for (int ks = 0; ks < 2; ++ks)
        xD[mt][ks] = *(const s16x8*)(dhT_s + row*128 + swzb(row, (ks*32+lg*8)*2)); }
    s16x8 yB[4][2];
    #pragma unroll
    for (int n0l = 0; n0l < 4; ++n0l){
      int hid = w*64 + n0l*16 + lr16;
      #pragma unroll
      for (int ks = 0; ks < 2; ++ks){
        s16x8 v;
        #pragma unroll
        for (int e = 0; e < 8; ++e){ int tok = ks*32 + lg*8 + e;
          v[e] = *(const short*)(a_s + tok*1024 + swza(tok, hid*2)); }
        yB[n0l][ks] = v;
      }
    }
    #pragma unroll 2
    for (int mt = 0; mt < 8; ++mt){
      #pragma unroll
      for (int n0l = 0; n0l < 4; ++n0l){
        f32x4 acc = {0.f,0.f,0.f,0.f};
        acc = MFMA(xD[mt][0], yB[n0l][0], acc);
        acc = MFMA(xD[mt][1], yB[n0l][1], acc);
        int hid = w*64 + n0l*16 + lr16;
        #pragma unroll
        for (int j = 0; j < 4; ++j)
          SW1[bc*65536 + (size_t)(mt*16 + lg*4 + j)*512 + hid] = f2bf(-acc[j]);
      }
    }
  }
  __syncthreads();   // a_s dead -> duT

  // ---- B2: duT[512 hid][64 tok] = (dh @ w1^T) * up.  m=tok, n=hid(w*64..), k=d ----
  {
    s16x8 xDh[4][4];
    #pragma unroll
    for (int mt = 0; mt < 4; ++mt){ int row = mt*16 + lr16;
      #pragma unroll
      for (int ks = 0; ks < 4; ++ks)
        xDh[mt][ks] = *(const s16x8*)(dh_s + row*256 + swzb(row, (ks*32+lg*8)*2)); }
    const u16* w1b = w1bf + (size_t)bh*65536;
    #pragma unroll 2
    for (int n0l = 0; n0l < 4; ++n0l){
      int hid = w*64 + n0l*16 + lr16;
      s16x8 yW[4];
      #pragma unroll
      for (int ks = 0; ks < 4; ++ks)
        yW[ks] = *(const s16x8*)(w1b + (size_t)hid*128 + ks*32 + lg*8);
      #pragma unroll
      for (int mt = 0; mt < 4; ++mt){
        f32x4 acc = {0.f,0.f,0.f,0.f};
        #pragma unroll
        for (int ks = 0; ks < 4; ++ks) acc = MFMA(xDh[mt][ks], yW[ks], acc);
        int tk0 = mt*16 + lg*4;
        uint2 ur = *(const uint2*)(upT_s + hid*128 + swzb(hid, tk0*2));
        float u0 = bf2f((u16)(ur.x & 0xffff)), u1 = bf2f((u16)(ur.x >> 16));
        float u2 = bf2f((u16)(ur.y & 0xffff)), u3 = bf2f((u16)(ur.y >> 16));
        *(uint2*)(duT_s + hid*128 + swzb(hid, tk0*2)) =
            make_uint2(pack2(acc[0]*u0, acc[1]*u1), pack2(acc[2]*u2, acc[3]*u3));
      }
    }
  }
  __syncthreads();   // upT dead -> kcT

  // ---- build kcT[128 d][64 tok] from global kc ----
  #pragma unroll
  for (int i = 0; i < 2; ++i){
    int idx = i*512 + t;
    int tok = idx & 63, d0 = (idx >> 6)*8;
    s16x8 kv = *(const s16x8*)(kc_g + (size_t)tok*128 + d0);
    #pragma unroll
    for (int e = 0; e < 8; ++e)
      *(u16*)(kcT_s + (d0+e)*128 + swzb(d0+e, tok*2)) = kv[e];
  }
  __syncthreads();

  // ---- B3: SW0[512 hid][128 d] = -(duT @ kc). A=duT rows, B=kcT rows ----
  {
    s16x8 xU[4][2];
    #pragma unroll
    for (int mi = 0; mi < 4; ++mi){ int hid = w*64 + mi*16 + lr16;
      #pragma unroll
      for (int ks = 0; ks < 2; ++ks)
        xU[mi][ks] = *(const s16x8*)(duT_s + hid*128 + swzb(hid, (ks*32+lg*8)*2)); }
    #pragma unroll 2
    for (int n0 = 0; n0 < 8; ++n0){
      int d = n0*16 + lr16;
      s16x8 yK[2];
      #pragma unroll
      for (int ks = 0; ks < 2; ++ks)
        yK[ks] = *(const s16x8*)(kcT_s + d*128 + swzb(d, (ks*32+lg*8)*2));
      #pragma unroll
      for (int mi = 0; mi < 4; ++mi){
        f32x4 acc = {0.f,0.f,0.f,0.f};
        acc = MFMA(xU[mi][0], yK[0], acc);
        acc = MFMA(xU[mi][1], yK[1], acc);
        #pragma unroll
        for (int j = 0; j < 4; ++j)
          SW0[bc*65536 + (size_t)(w*64 + mi*16 + lg*4 + j)*128 + d] = f2bf(-acc[j]);
      }
    }
  }
}

// ---------------- scans (f32 state, bf16 storage) ----------------
__global__ __launch_bounds__(256) void k_scan(
    const u16* __restrict__ w0T, const u16* __restrict__ w1T, const float* __restrict__ mg,
    const u16* __restrict__ SW0, const u16* __restrict__ SW1, const float* __restrict__ SG,
    const float* __restrict__ momb, const float* __restrict__ decb,
    u16* __restrict__ W0C, u16* __restrict__ W1C, float* __restrict__ GC){
  int bh = blockIdx.y;
  int e = blockIdx.x*256 + threadIdx.x;
  const float* momp = momb + bh*NCH;
  const float* decp = decb + bh*NCH;
  float m = 0.f, Wv;
  if (e < 65536){
    Wv = bf2f(w0T[(size_t)bh*65536 + e]);
    const u16* su = SW0 + (size_t)bh*NCH*65536 + e;
    u16* outp = W0C + (size_t)bh*NCH*65536 + e;
    for (int c = 0; c < NCH; ++c){
      outp[(size_t)c*65536] = f2bf(Wv);
      m = momp[c]*m + bf2f(su[(size_t)c*65536]);
      Wv = (1.f - decp[c])*Wv + m;
    }
  } else if (e < 131072){
    int e2 = e - 65536;
    Wv = bf2f(w1T[(size_t)bh*65536 + e2]);
    const u16* su = SW1 + (size_t)bh*NCH*65536 + e2;
    u16* outp = W1C + (size_t)bh*NCH*65536 + e2;
    for (int c = 0; c < NCH; ++c){
      outp[(size_t)c*65536] = f2bf(Wv);
      m = momp[c]*m + bf2f(su[(size_t)c*65536]);
      Wv = (1.f - decp[c])*Wv + m;
    }
  } else if (e < 131200){
    int e3 = e - 131072;
    Wv = mg[(size_t)bh*128 + e3];
    const float* su = SG + (size_t)bh*NCH*128 + e3;
    float* outp = GC + (size_t)bh*NCH*128 + e3;
    for (int c = 0; c < NCH; ++c){
      outp[(size_t)c*128] = Wv;
      m = momp[c]*m + su[(size_t)c*128];
      Wv = (1.f - decp[c])*Wv + m;
    }
  }
}

// ---------------- retrieval (512 threads, 8 waves) ----------------
__global__ __launch_bounds__(512) void k_retr(
    const u16* __restrict__ Qc, const u16* __restrict__ W0C, const u16* __restrict__ W1C,
    const float* __restrict__ GC, const float* __restrict__ gate, u16* __restrict__ OH){
  extern __shared__ char sm[];
  char* a_s = sm;                      // [64][512] swza
  float* scr = (float*)(sm + 65536);   // [128]
  int c = blockIdx.x, bh = blockIdx.y, t = threadIdx.x;
  size_t bc = (size_t)bh*NCH + c;
  int l = t & 63, w = t >> 6, lr16 = l & 15, lg = l >> 4;
  int tg = w & 3, dhf = w >> 2;
  const u16* q_g = Qc + bc*8192;

  s16x8 xq[4];
  #pragma unroll
  for (int k = 0; k < 4; ++k)
    xq[k] = *(const s16x8*)(q_g + (size_t)(tg*16+lr16)*128 + k*32 + lg*8);
  const u16* w0c = W0C + bc*65536;
  for (int n0h = 0; n0h < 16; ++n0h){
    int n0 = dhf*16 + n0h;
    f32x4 acc = {0.f,0.f,0.f,0.f};
    const u16* yb = w0c + (size_t)(n0*16 + lr16)*128 + lg*8;
    #pragma unroll
    for (int k = 0; k < 4; ++k) acc = MFMA(xq[k], *(const s16x8*)(yb + k*32), acc);
    int hid = n0*16 + lr16;
    #pragma unroll
    for (int j = 0; j < 4; ++j){
      int tok = tg*16 + lg*4 + j;
      float u = acc[j];
      float av = u*0.5f*(1.f + erff(u*0.70710678118654752f));
      *(u16*)(a_s + tok*1024 + swza(tok, hid*2)) = f2bf(av);
    }
  }
  __syncthreads();
  s16x8 xa[16];
  #pragma unroll
  for (int k = 0; k < 16; ++k){ int row = tg*16 + lr16;
    xa[k] = *(const s16x8*)(a_s + row*1024 + swza(row, (k*32+lg*8)*2)); }
  const u16* w1c = W1C + bc*65536;
  f32x4 hD[4];
  #pragma unroll
  for (int n0l = 0; n0l < 4; ++n0l){
    int d = dhf*64 + n0l*16 + lr16;
    f32x4 acc = {0.f,0.f,0.f,0.f};
    const u16* yb = w1c + (size_t)d*512 + lg*8;
    #pragma unroll
    for (int k = 0; k < 16; ++k) acc = MFMA(xa[k], *(const s16x8*)(yb + k*32), acc);
    hD[n0l] = acc;
  }
  #pragma unroll
  for (int j = 0; j < 4; ++j){
    float s = 0.f;
    #pragma unroll
    for (int n0l = 0; n0l < 4; ++n0l) s += hD[n0l][j]*hD[n0l][j];
    s += __shfl_xor(s,1); s += __shfl_xor(s,2); s += __shfl_xor(s,4); s += __shfl_xor(s,8);
    if (lr16 == 0) scr[dhf*64 + tg*16 + lg*4 + j] = s;
  }
  __syncthreads();
  float rv[4], gtv[4];
  #pragma unroll
  for (int j = 0; j < 4; ++j){
    int tok = tg*16 + lg*4 + j;
    rv[j] = rsqrtf((scr[tok] + scr[64 + tok])*(1.f/128.f) + 1e-6f);
    gtv[j] = gate[(size_t)(c*64 + tok)*8 + bh];
  }
  #pragma unroll
  for (int n0l = 0; n0l < 4; ++n0l){
    int d = dhf*64 + n0l*16 + lr16;
    float g0 = GC[bc*128 + d];
    #pragma unroll
    for (int j = 0; j < 4; ++j){
      int tok = tg*16 + lg*4 + j; int tokg = c*64 + tok;
      float qv = bf2f(q_g[(size_t)tok*128 + d]);
      float p = hD[n0l][j]*rv[j]*g0 + qv;
      OH[(size_t)tokg*1024 + bh*128 + d] = f2bf(p*gtv[j]);
    }
  }
}

// ---------------- launch ----------------
extern "C" void kernel_launch(void* const* d_in, const int* in_sizes, int n_in,
                              void* d_out, int out_size, void* d_ws, size_t ws_size,
                              hipStream_t stream) {
  (void)in_sizes; (void)n_in; (void)out_size; (void)ws_size;
  const float* x     = (const float*)d_in[0];
  const float* snw   = (const float*)d_in[1];
  const float* rnw   = (const float*)d_in[2];
  const float* Wq    = (const float*)d_in[3];
  const float* Wk    = (const float*)d_in[4];
  const float* Wv    = (const float*)d_in[5];
  const float* Wstep = (const float*)d_in[6];
  const float* bstep = (const float*)d_in[7];
  const float* Wmom  = (const float*)d_in[8];
  const float* bmom  = (const float*)d_in[9];
  const float* Wdec  = (const float*)d_in[10];
  const float* bdec  = (const float*)d_in[11];
  const float* gateW = (const float*)d_in[12];
  const float* combW = (const float*)d_in[13];
  const float* mw0   = (const float*)d_in[14];
  const float* mw1   = (const float*)d_in[15];
  const float* mg    = (const float*)d_in[16];
  float* out = (float*)d_out;

  char* Wb = (char*)d_ws;
  u16* Qc    = (u16*)(Wb + 0*MB);
  u16* Kc    = (u16*)(Wb + 4*MB);
  u16* Vc    = (u16*)(Wb + 8*MB);
  u16* s_bf  = (u16*)(Wb + 12*MB);
  u16* r_bf  = (u16*)(Wb + 16*MB);
  u16* WqT   = (u16*)(Wb + 20*MB);
  u16* WkT   = (u16*)(Wb + 22*MB);
  u16* WvT   = (u16*)(Wb + 24*MB);
  u16* combT = (u16*)(Wb + 26*MB);
  u16* w0T   = (u16*)(Wb + 28*MB);
  u16* w1T   = (u16*)(Wb + 29*MB);
  u16* w1bf  = (u16*)(Wb + 30*MB);
  u16* OH    = (u16*)(Wb + 31*MB);
  u16* SW0   = (u16*)(Wb + 35*MB);
  u16* SW1   = (u16*)(Wb + 67*MB);
  u16* W0C   = (u16*)(Wb + 99*MB);
  u16* W1C   = (u16*)(Wb + 131*MB);
  float* pooled = (float*)(Wb + 163*MB);
  float* lrc    = (float*)(Wb + 163*MB + 131072);
  float* momb   = (float*)(Wb + 163*MB + 196608);
  float* decb   = (float*)(Wb + 163*MB + 197632);
  float* gate   = (float*)(Wb + 163*MB + 198656);
  float* SG     = (float*)(Wb + 163*MB + 264192);
  float* GC     = (float*)(Wb + 163*MB + 395264);

  hipFuncSetAttribute((const void*)k_grad, hipFuncAttributeMaxDynamicSharedMemorySize, 163840);
  hipFuncSetAttribute((const void*)k_retr, hipFuncAttributeMaxDynamicSharedMemorySize, 66560);

  k_rmsnorm<<<2048, 256, 0, stream>>>(x, snw, rnw, s_bf, r_bf);
  k_pool<<<dim3(32,4), 256, 0, stream>>>(s_bf, pooled);
  k_lrgate<<<512, 256, 0, stream>>>(s_bf, r_bf, Wstep, bstep, gateW, lrc, gate);
  k_momdec<<<32, 64, 0, stream>>>(pooled, Wmom, bmom, Wdec, bdec, momb, decb);
  k_trf4<<<dim3(32,32,4), 256, 0, stream>>>(Wq, Wk, Wv, combW, WqT, WkT, WvT, combT);
  k_trf<<<dim3(16,4,8), 256, 0, stream>>>(mw0, w0T, 128, 512);
  k_trf<<<dim3(4,16,8), 256, 0, stream>>>(mw1, w1T, 512, 128);
  k_cast<<<2048, 256, 0, stream>>>(mw1, w1bf, 524288);
  k_gemm3<<<dim3(32,16,3), 256, 0, stream>>>(s_bf, r_bf, WkT, WvT, WqT, Kc, Vc, Qc);
  k_grad<<<dim3(32,8), 512, 163840, stream>>>(Kc, Vc, lrc, w0T, w1T, w1bf, mg, SW0, SW1, SG);
  k_scan<<<dim3(513,8), 256, 0, stream>>>(w0T, w1T, mg, SW0, SW1, SG, momb, decb, W0C, W1C, GC);
  k_retr<<<dim3(32,8), 512, 66560, stream>>>(Qc, W0C, W1C, GC, gate, OH);
  k_gemm_bf<<<dim3(32,16), 256, 0, stream>>>(OH, combT, (void*)out, 0);
}